// Round 14
// baseline (1825.497 us; speedup 1.0000x reference)
//
#include <hip/hip_runtime.h>
#include <stdint.h>
#include <math.h>

// Problem constants
#define NN    50000       // N_NODES
#define NE    400000      // N_EDGES
#define NL    50000       // N_LINKS
#define TOT   12800000    // NN*256

#define JAX_PARTITIONABLE 1

struct K8 { uint32_t a[4]; uint32_t b[4]; };

// ---------------- Threefry-2x32 (20 rounds) ----------------
__host__ __device__ inline uint32_t rotl32(uint32_t x, int r){ return (x<<r)|(x>>(32-r)); }

__host__ __device__ inline void tf2x32(uint32_t k0, uint32_t k1, uint32_t x0, uint32_t x1,
                                       uint32_t &o0, uint32_t &o1) {
  uint32_t k2 = k0 ^ k1 ^ 0x1BD11BDAu;
  x0 += k0; x1 += k1;
#define TFR(r) { x0 += x1; x1 = rotl32(x1,(r)); x1 ^= x0; }
  TFR(13) TFR(15) TFR(26) TFR(6)
  x0 += k1; x1 += k2 + 1u;
  TFR(17) TFR(29) TFR(16) TFR(24)
  x0 += k2; x1 += k0 + 2u;
  TFR(13) TFR(15) TFR(26) TFR(6)
  x0 += k0; x1 += k1 + 3u;
  TFR(17) TFR(29) TFR(16) TFR(24)
  x0 += k1; x1 += k2 + 4u;
  TFR(13) TFR(15) TFR(26) TFR(6)
  x0 += k2; x1 += k0 + 5u;
#undef TFR
  o0 = x0; o1 = x1;
}

__device__ inline float u01(uint32_t b){
  return __uint_as_float((b>>9) | 0x3f800000u) - 1.0f;   // [1,2) - 1, exact
}

__device__ inline uint32_t jax_bits32(uint32_t ka, uint32_t kb, uint32_t i, uint32_t total){
#if JAX_PARTITIONABLE
  uint32_t o0,o1; tf2x32(ka,kb, 0u, i, o0,o1); return o0^o1;
#else
  uint32_t h = total>>1; uint32_t o0,o1;
  if (i < h){ tf2x32(ka,kb, i, i+h, o0,o1); return o0; }
  else      { tf2x32(ka,kb, i-h, i, o0,o1); return o1; }
#endif
}

__device__ inline double shflxor_d(double x, int m){
  union { double d; int i[2]; } u; u.d = x;
  u.i[0] = __shfl_xor(u.i[0], m, 64);
  u.i[1] = __shfl_xor(u.i[1], m, 64);
  return u.d;
}

// exact fp32 LIF step: v = fl(fl(v*0.5)+a); d = fl(v-0.2); s=(d>=0); v = s?d:v
__device__ inline bool lif32(float &v, float a){
  v = __fadd_rn(__fmul_rn(v, 0.5f), a);
  float d = __fsub_rn(v, 0.2f);
  bool s = (d >= 0.0f);
  v = s ? d : v;
  return s;
}

// force a value to live in a VGPR
#define FORCE_V(x) asm volatile("" : "+v"(x))

// wr if bit b of w set, else +0.0f — used in decoder (small)
__device__ inline float bitmaskf(uint32_t w, int b, float wr){
#if __has_builtin(__builtin_amdgcn_sbfe)
  int m = __builtin_amdgcn_sbfe((int)w, b, 1);
#else
  int m = ((int)(w << (31-b))) >> 31;
#endif
  return __int_as_float(__float_as_int(wr) & m);
}

// ---------------- CSR build (by dst), deterministic edge order ----------------
__global__ __launch_bounds__(256) void k_hist(const int* __restrict__ dst, int* __restrict__ cnt){
  int e = blockIdx.x*256 + threadIdx.x;
  if (e < NE) atomicAdd(&cnt[dst[e]], 1);
}

// wave-shuffle scan: 3 barriers per 1024-chunk (was ~20)
__global__ __launch_bounds__(1024) void k_scan(const int* __restrict__ cnt,
    int* __restrict__ rp, int* __restrict__ cur){
  __shared__ int ws[16];
  __shared__ int wp[17];
  int tid = threadIdx.x;
  int lane = tid & 63, wid = tid >> 6;
  int carry = 0;
  for (int base=0; base<NN; base+=1024){
    int v = (base+tid < NN) ? cnt[base+tid] : 0;
    int x = v;
    #pragma unroll
    for (int off=1; off<64; off<<=1){
      int u = __shfl_up(x, off, 64);
      if (lane >= off) x += u;
    }
    if (lane==63) ws[wid] = x;
    __syncthreads();
    if (wid==0){
      int s = (lane<16) ? ws[lane] : 0;
      #pragma unroll
      for (int off=1; off<16; off<<=1){
        int u = __shfl_up(s, off, 64);
        if (lane >= off) s += u;
      }
      if (lane<16) wp[lane+1] = s;
      if (lane==0) wp[0] = 0;
    }
    __syncthreads();
    int excl = x - v + wp[wid] + carry;
    if (base+tid < NN){ rp[base+tid] = excl; cur[base+tid] = excl; }
    carry += wp[16];
    __syncthreads();
  }
  if (tid==0) rp[NN] = NE;
}

__global__ __launch_bounds__(256) void k_scatter(const int* __restrict__ dst,
    int* __restrict__ cur, int* __restrict__ eidx){
  int e = blockIdx.x*256 + threadIdx.x;
  if (e < NE){ int p = atomicAdd(&cur[dst[e]], 1); eidx[p] = e; }
}

__global__ __launch_bounds__(256) void k_sortrow(const int* __restrict__ rp,
    int* __restrict__ eidx, const int* __restrict__ esrc, const float* __restrict__ ew,
    int* __restrict__ csrc, float* __restrict__ cw){
  int n = blockIdx.x*256 + threadIdx.x;
  if (n >= NN) return;
  int lo = rp[n], hi = rp[n+1];
  for (int a=lo+1; a<hi; a++){
    int k = eidx[a]; int b = a-1;
    while (b>=lo && eidx[b]>k){ eidx[b+1]=eidx[b]; b--; }
    eidx[b+1] = k;
  }
  for (int p=lo; p<hi; p++){ int e = eidx[p]; csrc[p] = esrc[e]; cw[p] = ew[e]; }
}

// Plane layouts (t innermost, 32B per (node,word)):
//   inpb/hs0b/zs0b : [node][w(4)][t(4)]   (NN*16 words)
//   hs1b           : [node][w(8)][t(4)]   (NN*32 words)
//   zs1b           : [node][w(2)][t(4)]   (NN*8  words)

// ---------------- Stage A: inp(t) = poisson(x, k1[t]) ----------------
__global__ __launch_bounds__(256) void k_pois_x(const float* __restrict__ x,
    uint64_t* __restrict__ bits, K8 K){
  int n = blockIdx.x, f = threadIdx.x;
  uint32_t i = (uint32_t)n*256u + (uint32_t)f;
  float xv = x[i];
  uint64_t pack[4];
  #pragma unroll
  for (int t=0;t<4;t++){
    bool b = (u01(jax_bits32(K.a[t],K.b[t], i, TOT)) <= xv);
    pack[t] = __ballot(b);
  }
  if ((f & 63)==0){
    uint64_t* dst = bits + ((size_t)n*4 + (f>>6))*4;
    #pragma unroll
    for (int t=0;t<4;t++) dst[t] = pack[t];
  }
}

// ---------------- Stage B: h0(t) fp32 gather (edge order) + poisson(h0,k2) ----------------
// 1-deep software pipeline: issue edge p+1's loads before accumulating edge p.
// fp32 add ORDER is unchanged (exactness vs reference preserved).
__global__ __launch_bounds__(256) void k_h0(const int* __restrict__ rp,
    const int* __restrict__ csrc, const float* __restrict__ cw,
    const uint64_t* __restrict__ inb, uint64_t* __restrict__ outb, K8 K){
  int n = blockIdx.x, f = threadIdx.x;
  int wi = f>>6, sh = f&63;
  int lo = rp[n], hi = rp[n+1];
  float a[4] = {0.f,0.f,0.f,0.f};
  if (lo < hi){
    int s = csrc[lo];
    float w = cw[lo];
    const uint64_t* bp = inb + ((size_t)s*4 + wi)*4;
    uint64_t b0=bp[0], b1=bp[1], b2=bp[2], b3=bp[3];
    for (int p=lo+1; p<hi; p++){
      int s2 = csrc[p];
      float w2 = cw[p];
      const uint64_t* bp2 = inb + ((size_t)s2*4 + wi)*4;
      uint64_t n0=bp2[0], n1=bp2[1], n2=bp2[2], n3=bp2[3];
      a[0] = __fadd_rn(a[0], ((b0>>sh)&1ull) ? w : 0.0f);
      a[1] = __fadd_rn(a[1], ((b1>>sh)&1ull) ? w : 0.0f);
      a[2] = __fadd_rn(a[2], ((b2>>sh)&1ull) ? w : 0.0f);
      a[3] = __fadd_rn(a[3], ((b3>>sh)&1ull) ? w : 0.0f);
      b0=n0; b1=n1; b2=n2; b3=n3; w=w2;
    }
    a[0] = __fadd_rn(a[0], ((b0>>sh)&1ull) ? w : 0.0f);
    a[1] = __fadd_rn(a[1], ((b1>>sh)&1ull) ? w : 0.0f);
    a[2] = __fadd_rn(a[2], ((b2>>sh)&1ull) ? w : 0.0f);
    a[3] = __fadd_rn(a[3], ((b3>>sh)&1ull) ? w : 0.0f);
  }
  uint32_t i = (uint32_t)n*256u + (uint32_t)f;
  uint64_t pack[4];
  #pragma unroll
  for (int t=0;t<4;t++){
    bool b = (u01(jax_bits32(K.a[t],K.b[t], i, TOT)) <= a[t]);
    pack[t] = __ballot(b);
  }
  if (sh==0){
    uint64_t* dst = outb + ((size_t)n*4 + wi)*4;
    #pragma unroll
    for (int t=0;t<4;t++) dst[t] = pack[t];
  }
}

// ---------------- Stage C: z0 = LIF_t(hs0 @ W1)  (K=256, M=256) ----------------
// 16 nodes/block (4 waves x 4-node group), 4 cols/thread (col = lane+64cc).
// Per q: 4 coalesced wr loads + 4 broadcast ds_read_b128 + 128 v_fma (1:16 ratio).
__global__ __launch_bounds__(256, 2) void k_z0(const uint64_t* __restrict__ inb,
    const float* __restrict__ W, uint64_t* __restrict__ outb){
  __shared__ __align__(16) float sp[16*64*4];    // [i(16)][k(64)][t(4)] 16KB
  int tid = threadIdx.x;
  int g = tid>>6, lane = tid&63;                 // wave = node group
  int n0 = blockIdx.x*16;
  float acc[4][4][4];                            // [t][i][cc]
  #pragma unroll
  for (int t=0;t<4;t++)
    #pragma unroll
    for (int i=0;i<4;i++)
      #pragma unroll
      for (int c=0;c<4;c++) acc[t][i][c]=0.0f;

  for (int kt=0; kt<4; kt++){
    #pragma unroll
    for (int rep=0; rep<4; rep++){
      int idx = rep*256 + tid;
      int i = idx>>6, k = idx&63;
      const uint64_t* bp = inb + (((size_t)(n0+i))*4 + kt)*4;
      uint64_t w0=bp[0], w1=bp[1], w2=bp[2], w3=bp[3];
      float4 f;
      f.x = ((w0>>k)&1ull) ? 1.0f : 0.0f;
      f.y = ((w1>>k)&1ull) ? 1.0f : 0.0f;
      f.z = ((w2>>k)&1ull) ? 1.0f : 0.0f;
      f.w = ((w3>>k)&1ull) ? 1.0f : 0.0f;
      *(float4*)&sp[(i*64+k)*4] = f;
    }
    __syncthreads();
    const float* Wrow = W + (size_t)(kt*64)*256 + lane;
    #pragma unroll 4
    for (int q=0;q<64;q++){
      const float* wb = Wrow + (size_t)q*256;
      float wr0 = wb[0], wr1 = wb[64], wr2 = wb[128], wr3 = wb[192];
      float4 s0 = *(const float4*)&sp[((g*4+0)*64+q)*4];
      float4 s1 = *(const float4*)&sp[((g*4+1)*64+q)*4];
      float4 s2 = *(const float4*)&sp[((g*4+2)*64+q)*4];
      float4 s3 = *(const float4*)&sp[((g*4+3)*64+q)*4];
      #define FMA4(ti, sv) \
        acc[ti][0][0]=__fmaf_rn(s0.sv,wr0,acc[ti][0][0]); acc[ti][0][1]=__fmaf_rn(s0.sv,wr1,acc[ti][0][1]); \
        acc[ti][0][2]=__fmaf_rn(s0.sv,wr2,acc[ti][0][2]); acc[ti][0][3]=__fmaf_rn(s0.sv,wr3,acc[ti][0][3]); \
        acc[ti][1][0]=__fmaf_rn(s1.sv,wr0,acc[ti][1][0]); acc[ti][1][1]=__fmaf_rn(s1.sv,wr1,acc[ti][1][1]); \
        acc[ti][1][2]=__fmaf_rn(s1.sv,wr2,acc[ti][1][2]); acc[ti][1][3]=__fmaf_rn(s1.sv,wr3,acc[ti][1][3]); \
        acc[ti][2][0]=__fmaf_rn(s2.sv,wr0,acc[ti][2][0]); acc[ti][2][1]=__fmaf_rn(s2.sv,wr1,acc[ti][2][1]); \
        acc[ti][2][2]=__fmaf_rn(s2.sv,wr2,acc[ti][2][2]); acc[ti][2][3]=__fmaf_rn(s2.sv,wr3,acc[ti][2][3]); \
        acc[ti][3][0]=__fmaf_rn(s3.sv,wr0,acc[ti][3][0]); acc[ti][3][1]=__fmaf_rn(s3.sv,wr1,acc[ti][3][1]); \
        acc[ti][3][2]=__fmaf_rn(s3.sv,wr2,acc[ti][3][2]); acc[ti][3][3]=__fmaf_rn(s3.sv,wr3,acc[ti][3][3]);
      FMA4(0, x) FMA4(1, y) FMA4(2, z) FMA4(3, w)
      #undef FMA4
    }
    __syncthreads();
  }

  #pragma unroll
  for (int i=0;i<4;i++){
    int node = n0 + g*4 + i;
    float v[4] = {0.f,0.f,0.f,0.f};
    #pragma unroll
    for (int t=0;t<4;t++){
      uint64_t b[4];
      #pragma unroll
      for (int c=0;c<4;c++){
        bool s = lif32(v[c], acc[t][i][c]);
        b[c] = __ballot(s);
      }
      if (lane==0){
        #pragma unroll
        for (int c=0;c<4;c++) outb[((size_t)node*4 + c)*4 + t] = b[c];
      }
    }
  }
}

// ---------------- Stage D: h1(t) gather over concat(zs0,hs0), LIF -> hs1 ----------------
// Same 1-deep software pipeline as k_h0; add order unchanged.
__global__ __launch_bounds__(512) void k_h1(const int* __restrict__ rp,
    const int* __restrict__ csrc, const float* __restrict__ cw,
    const uint64_t* __restrict__ zs0b, const uint64_t* __restrict__ hs0b,
    uint64_t* __restrict__ hs1b){
  int n = blockIdx.x, f = threadIdx.x;           // f in [0,512)
  int wi = f>>6, sh = f&63;
  const uint64_t* plane = (wi<4) ? zs0b : hs0b;
  int wo = wi & 3;
  int lo = rp[n], hi = rp[n+1];
  float a[4] = {0.f,0.f,0.f,0.f};
  if (lo < hi){
    int s = csrc[lo];
    float w = cw[lo];
    const uint64_t* bp = plane + ((size_t)s*4 + wo)*4;
    uint64_t b0=bp[0], b1=bp[1], b2=bp[2], b3=bp[3];
    for (int p=lo+1; p<hi; p++){
      int s2 = csrc[p];
      float w2 = cw[p];
      const uint64_t* bp2 = plane + ((size_t)s2*4 + wo)*4;
      uint64_t n0=bp2[0], n1=bp2[1], n2=bp2[2], n3=bp2[3];
      a[0] = __fadd_rn(a[0], ((b0>>sh)&1ull) ? w : 0.0f);
      a[1] = __fadd_rn(a[1], ((b1>>sh)&1ull) ? w : 0.0f);
      a[2] = __fadd_rn(a[2], ((b2>>sh)&1ull) ? w : 0.0f);
      a[3] = __fadd_rn(a[3], ((b3>>sh)&1ull) ? w : 0.0f);
      b0=n0; b1=n1; b2=n2; b3=n3; w=w2;
    }
    a[0] = __fadd_rn(a[0], ((b0>>sh)&1ull) ? w : 0.0f);
    a[1] = __fadd_rn(a[1], ((b1>>sh)&1ull) ? w : 0.0f);
    a[2] = __fadd_rn(a[2], ((b2>>sh)&1ull) ? w : 0.0f);
    a[3] = __fadd_rn(a[3], ((b3>>sh)&1ull) ? w : 0.0f);
  }
  float v = 0.0f;
  uint64_t pack[4];
  #pragma unroll
  for (int t=0;t<4;t++){
    bool s = lif32(v, a[t]);
    pack[t] = __ballot(s);
  }
  if (sh==0){
    uint64_t* dst = hs1b + ((size_t)n*8 + wi)*4;
    #pragma unroll
    for (int t=0;t<4;t++) dst[t] = pack[t];
  }
}

// ---------------- Stage E: z1 = LIF_t(hs1 @ W2)  (K=512, M=128) ----------------
// v3: 32 nodes/block (4 waves x 8-node group), 256 threads, 2 cols/thread
// (col = lane + 64*c). 64 FMA per q per thread vs 2 W loads -> 2x FMA density
// of v2. Per-(node,col,t) FMA order over (kt,q) unchanged -> bit-exact.
// Tail block (node >= NN) computes garbage but stores are guarded; its staging
// reads stay inside the workspace (zs1b follows hs1b).
__global__ __launch_bounds__(256, 2) void k_z1(const uint64_t* __restrict__ inb,
    const float* __restrict__ W, uint64_t* __restrict__ outb){
  __shared__ __align__(16) float sp[32*64*4];    // [i(32)][k(64)][t(4)] 32KB
  int tid = threadIdx.x;
  int g = tid>>6, lane = tid&63;                 // wave = 8-node group
  int n0 = blockIdx.x*32;
  float acc[4][8][2];                            // [t][i][c]
  #pragma unroll
  for (int t=0;t<4;t++)
    #pragma unroll
    for (int i=0;i<8;i++){ acc[t][i][0]=0.0f; acc[t][i][1]=0.0f; }

  for (int kt=0; kt<8; kt++){
    #pragma unroll
    for (int rep=0; rep<8; rep++){
      int idx = rep*256 + tid;                   // 0..2047
      int i = idx>>6, k = idx&63;                // i in [0,32)
      const uint64_t* bp = inb + (((size_t)(n0+i))*8 + kt)*4;
      uint64_t w0=bp[0], w1=bp[1], w2=bp[2], w3=bp[3];
      float4 f;
      f.x = ((w0>>k)&1ull) ? 1.0f : 0.0f;
      f.y = ((w1>>k)&1ull) ? 1.0f : 0.0f;
      f.z = ((w2>>k)&1ull) ? 1.0f : 0.0f;
      f.w = ((w3>>k)&1ull) ? 1.0f : 0.0f;
      *(float4*)&sp[(i*64+k)*4] = f;
    }
    __syncthreads();
    const float* Wrow = W + (size_t)(kt*64)*128 + lane;
    #pragma unroll 2
    for (int q=0;q<64;q++){
      const float* wb = Wrow + (size_t)q*128;
      float wr0 = wb[0], wr1 = wb[64];
      #pragma unroll
      for (int j=0;j<8;j++){
        float4 sj = *(const float4*)&sp[((g*8+j)*64+q)*4];
        acc[0][j][0]=__fmaf_rn(sj.x,wr0,acc[0][j][0]); acc[0][j][1]=__fmaf_rn(sj.x,wr1,acc[0][j][1]);
        acc[1][j][0]=__fmaf_rn(sj.y,wr0,acc[1][j][0]); acc[1][j][1]=__fmaf_rn(sj.y,wr1,acc[1][j][1]);
        acc[2][j][0]=__fmaf_rn(sj.z,wr0,acc[2][j][0]); acc[2][j][1]=__fmaf_rn(sj.z,wr1,acc[2][j][1]);
        acc[3][j][0]=__fmaf_rn(sj.w,wr0,acc[3][j][0]); acc[3][j][1]=__fmaf_rn(sj.w,wr1,acc[3][j][1]);
      }
    }
    __syncthreads();
  }

  #pragma unroll
  for (int i=0;i<8;i++){
    int node = n0 + g*8 + i;
    float v0 = 0.0f, v1 = 0.0f;
    #pragma unroll
    for (int t=0;t<4;t++){
      uint64_t b0, b1;
      { bool s = lif32(v0, acc[t][i][0]); b0 = __ballot(s); }   // cols 0..63
      { bool s = lif32(v1, acc[t][i][1]); b1 = __ballot(s); }   // cols 64..127
      if (lane==0 && node < NN){
        outb[((size_t)node*2 + 0)*4 + t] = b0;
        outb[((size_t)node*2 + 1)*4 + t] = b1;
      }
    }
  }
}

// ---------------- Stage F: decoder + y + sigmoid ----------------
__global__ __launch_bounds__(128) void k_dec_y(const int* __restrict__ ns,
    const int* __restrict__ nt, const uint64_t* __restrict__ zs1b,
    const float* __restrict__ Wd, const float* __restrict__ bd,
    const float* __restrict__ wrec, float* __restrict__ out){
  int i = blockIdx.x;
  int tid = threadIdx.x;
  int row = tid>>6, j = tid&63;
  int node = row ? nt[i] : ns[i];
  float bdj = bd[j];
  double wrecj = (double)wrec[j];
  __shared__ uint64_t sw[2];

  uint32_t wlo[2][4], whi[2][4];
  const uint64_t* bp = zs1b + (size_t)node*8;
  #pragma unroll
  for (int g=0;g<2;g++)
    #pragma unroll
    for (int t=0;t<4;t++){
      uint64_t w8 = bp[g*4+t];
      wlo[g][t] = (uint32_t)w8;
      whi[g][t] = (uint32_t)(w8>>32);
      FORCE_V(wlo[g][t]); FORCE_V(whi[g][t]);
    }

  float acc[4] = {0.f,0.f,0.f,0.f};
  #pragma unroll
  for (int g=0;g<2;g++){
    #pragma unroll
    for (int h=0;h<2;h++){
      #pragma unroll
      for (int c=0;c<2;c++){
        float wr[16];
        #pragma unroll
        for (int q=0;q<16;q++) wr[q] = Wd[(size_t)(g*64+h*32+c*16+q)*64 + j];
        #pragma unroll
        for (int q=0;q<16;q++){
          int b = c*16+q;
          #pragma unroll
          for (int t=0;t<4;t++){
            uint32_t wv = h ? whi[g][t] : wlo[g][t];
            acc[t] = __fadd_rn(acc[t], bitmaskf(wv, b, wr[q]));
          }
        }
      }
    }
  }

  float v = 0.0f;
  double ysum = 0.0;
  #pragma unroll
  for (int t=0;t<4;t++){
    float a = __fadd_rn(acc[t], bdj);
    bool s = lif32(v, a);
    uint64_t bw = __ballot(s);
    if (j==0) sw[row] = bw;
    __syncthreads();
    uint64_t m = sw[0] & sw[1];
    __syncthreads();
    double term = ((m>>j)&1ull) ? wrecj : 0.0;
    #pragma unroll
    for (int off=1; off<64; off<<=1) term += shflxor_d(term, off);
    ysum += term;
  }
  if (tid==0) out[i] = (float)(1.0/(1.0 + exp(-0.25*ysum)));
}

// ---------------- Launcher ----------------
extern "C" void kernel_launch(void* const* d_in, const int* in_sizes, int n_in,
                              void* d_out, int out_size, void* d_ws, size_t ws_size,
                              hipStream_t stream) {
  const float* x    = (const float*)d_in[0];
  const float* W1   = (const float*)d_in[1];
  const float* W2   = (const float*)d_in[2];
  const float* Wd   = (const float*)d_in[3];
  const float* bd   = (const float*)d_in[4];
  const float* wrec = (const float*)d_in[5];
  const float* ew   = (const float*)d_in[6];
  const int* esrc   = (const int*)d_in[7];
  const int* edst   = (const int*)d_in[8];
  const int* ns     = (const int*)d_in[9];
  const int* nt     = (const int*)d_in[10];
  float* out = (float*)d_out;
  (void)in_sizes; (void)n_in; (void)out_size; (void)ws_size;

  // workspace layout (~41 MB)
  char* p = (char*)d_ws;
  uint64_t* inpb = (uint64_t*)p; p += (size_t)NN*16*8;
  uint64_t* hs0b = (uint64_t*)p; p += (size_t)NN*16*8;
  uint64_t* zs0b = (uint64_t*)p; p += (size_t)NN*16*8;
  uint64_t* hs1b = (uint64_t*)p; p += (size_t)NN*32*8;
  uint64_t* zs1b = (uint64_t*)p; p += (size_t)NN*8*8;
  int*   eidx = (int*)p;   p += (size_t)NE*4;
  int*   csrc = (int*)p;   p += (size_t)NE*4;
  float* cw   = (float*)p; p += (size_t)NE*4;
  int*   cnt  = (int*)p;   p += (size_t)(NN+2)*4;
  int*   rp   = (int*)p;   p += (size_t)(NN+2)*4;
  int*   cur  = (int*)p;   p += (size_t)(NN+2)*4;

  // host-side key chain: key=(0,42); kt=fold_in(key,t); k1,k2=split(kt)
  K8 K1, K2;
  for (int t=0;t<4;t++){
    uint32_t kt0,kt1;
    tf2x32(0u, 42u, 0u, (uint32_t)t, kt0, kt1);
#if JAX_PARTITIONABLE
    tf2x32(kt0, kt1, 0u, 0u, K1.a[t], K1.b[t]);
    tf2x32(kt0, kt1, 0u, 1u, K2.a[t], K2.b[t]);
#else
    uint32_t A0,B0,A1,B1;
    tf2x32(kt0, kt1, 0u, 2u, A0, B0);
    tf2x32(kt0, kt1, 1u, 3u, A1, B1);
    K1.a[t]=A0; K1.b[t]=A1; K2.a[t]=B0; K2.b[t]=B1;
#endif
  }

  // CSR build (deterministic via per-row sort by edge id)
  hipMemsetAsync(cnt, 0, (size_t)NN*4, stream);
  k_hist   <<<(NE+255)/256, 256, 0, stream>>>(edst, cnt);
  k_scan   <<<1, 1024, 0, stream>>>(cnt, rp, cur);
  k_scatter<<<(NE+255)/256, 256, 0, stream>>>(edst, cur, eidx);
  k_sortrow<<<(NN+255)/256, 256, 0, stream>>>(rp, eidx, esrc, ew, csrc, cw);

  // stage-major pipeline, all T=4 per kernel, LIF state in registers (fp32)
  k_pois_x<<<NN, 256, 0, stream>>>(x, inpb, K1);
  k_h0    <<<NN, 256, 0, stream>>>(rp, csrc, cw, inpb, hs0b, K2);
  k_z0    <<<NN/16, 256, 0, stream>>>(hs0b, W1, zs0b);
  k_h1    <<<NN, 512, 0, stream>>>(rp, csrc, cw, zs0b, hs0b, hs1b);
  k_z1    <<<(NN+31)/32, 256, 0, stream>>>(hs1b, W2, zs1b);
  k_dec_y <<<NL, 128, 0, stream>>>(ns, nt, zs1b, Wd, bd, wrec, out);
}

// Round 19
// 1598.232 us; speedup vs baseline: 1.1422x; 1.1422x over previous
//
#include <hip/hip_runtime.h>
#include <stdint.h>
#include <math.h>

// Problem constants
#define NN    50000       // N_NODES
#define NE    400000      // N_EDGES
#define NL    50000       // N_LINKS
#define TOT   12800000    // NN*256

#define JAX_PARTITIONABLE 1

struct K8 { uint32_t a[4]; uint32_t b[4]; };

// ---------------- Threefry-2x32 (20 rounds) ----------------
__host__ __device__ inline uint32_t rotl32(uint32_t x, int r){ return (x<<r)|(x>>(32-r)); }

__host__ __device__ inline void tf2x32(uint32_t k0, uint32_t k1, uint32_t x0, uint32_t x1,
                                       uint32_t &o0, uint32_t &o1) {
  uint32_t k2 = k0 ^ k1 ^ 0x1BD11BDAu;
  x0 += k0; x1 += k1;
#define TFR(r) { x0 += x1; x1 = rotl32(x1,(r)); x1 ^= x0; }
  TFR(13) TFR(15) TFR(26) TFR(6)
  x0 += k1; x1 += k2 + 1u;
  TFR(17) TFR(29) TFR(16) TFR(24)
  x0 += k2; x1 += k0 + 2u;
  TFR(13) TFR(15) TFR(26) TFR(6)
  x0 += k0; x1 += k1 + 3u;
  TFR(17) TFR(29) TFR(16) TFR(24)
  x0 += k1; x1 += k2 + 4u;
  TFR(13) TFR(15) TFR(26) TFR(6)
  x0 += k2; x1 += k0 + 5u;
#undef TFR
  o0 = x0; o1 = x1;
}

__device__ inline float u01(uint32_t b){
  return __uint_as_float((b>>9) | 0x3f800000u) - 1.0f;   // [1,2) - 1, exact
}

__device__ inline uint32_t jax_bits32(uint32_t ka, uint32_t kb, uint32_t i, uint32_t total){
#if JAX_PARTITIONABLE
  uint32_t o0,o1; tf2x32(ka,kb, 0u, i, o0,o1); return o0^o1;
#else
  uint32_t h = total>>1; uint32_t o0,o1;
  if (i < h){ tf2x32(ka,kb, i, i+h, o0,o1); return o0; }
  else      { tf2x32(ka,kb, i-h, i, o0,o1); return o1; }
#endif
}

__device__ inline double shflxor_d(double x, int m){
  union { double d; int i[2]; } u; u.d = x;
  u.i[0] = __shfl_xor(u.i[0], m, 64);
  u.i[1] = __shfl_xor(u.i[1], m, 64);
  return u.d;
}

// exact fp32 LIF step: v = fl(fl(v*0.5)+a); d = fl(v-0.2); s=(d>=0); v = s?d:v
__device__ inline bool lif32(float &v, float a){
  v = __fadd_rn(__fmul_rn(v, 0.5f), a);
  float d = __fsub_rn(v, 0.2f);
  bool s = (d >= 0.0f);
  v = s ? d : v;
  return s;
}

// force a value to live in a VGPR
#define FORCE_V(x) asm volatile("" : "+v"(x))

// wr if bit b of w set, else +0.0f — used in decoder (small)
__device__ inline float bitmaskf(uint32_t w, int b, float wr){
#if __has_builtin(__builtin_amdgcn_sbfe)
  int m = __builtin_amdgcn_sbfe((int)w, b, 1);
#else
  int m = ((int)(w << (31-b))) >> 31;
#endif
  return __int_as_float(__float_as_int(wr) & m);
}

// ---------------- CSR build (by dst), deterministic edge order ----------------
__global__ __launch_bounds__(256) void k_hist(const int* __restrict__ dst, int* __restrict__ cnt){
  int e = blockIdx.x*256 + threadIdx.x;
  if (e < NE) atomicAdd(&cnt[dst[e]], 1);
}

// wave-shuffle scan: 3 barriers per 1024-chunk (was ~20)
__global__ __launch_bounds__(1024) void k_scan(const int* __restrict__ cnt,
    int* __restrict__ rp, int* __restrict__ cur){
  __shared__ int ws[16];
  __shared__ int wp[17];
  int tid = threadIdx.x;
  int lane = tid & 63, wid = tid >> 6;
  int carry = 0;
  for (int base=0; base<NN; base+=1024){
    int v = (base+tid < NN) ? cnt[base+tid] : 0;
    int x = v;
    #pragma unroll
    for (int off=1; off<64; off<<=1){
      int u = __shfl_up(x, off, 64);
      if (lane >= off) x += u;
    }
    if (lane==63) ws[wid] = x;
    __syncthreads();
    if (wid==0){
      int s = (lane<16) ? ws[lane] : 0;
      #pragma unroll
      for (int off=1; off<16; off<<=1){
        int u = __shfl_up(s, off, 64);
        if (lane >= off) s += u;
      }
      if (lane<16) wp[lane+1] = s;
      if (lane==0) wp[0] = 0;
    }
    __syncthreads();
    int excl = x - v + wp[wid] + carry;
    if (base+tid < NN){ rp[base+tid] = excl; cur[base+tid] = excl; }
    carry += wp[16];
    __syncthreads();
  }
  if (tid==0) rp[NN] = NE;
}

__global__ __launch_bounds__(256) void k_scatter(const int* __restrict__ dst,
    int* __restrict__ cur, int* __restrict__ eidx){
  int e = blockIdx.x*256 + threadIdx.x;
  if (e < NE){ int p = atomicAdd(&cur[dst[e]], 1); eidx[p] = e; }
}

__global__ __launch_bounds__(256) void k_sortrow(const int* __restrict__ rp,
    int* __restrict__ eidx, const int* __restrict__ esrc, const float* __restrict__ ew,
    int* __restrict__ csrc, float* __restrict__ cw){
  int n = blockIdx.x*256 + threadIdx.x;
  if (n >= NN) return;
  int lo = rp[n], hi = rp[n+1];
  for (int a=lo+1; a<hi; a++){
    int k = eidx[a]; int b = a-1;
    while (b>=lo && eidx[b]>k){ eidx[b+1]=eidx[b]; b--; }
    eidx[b+1] = k;
  }
  for (int p=lo; p<hi; p++){ int e = eidx[p]; csrc[p] = esrc[e]; cw[p] = ew[e]; }
}

// Plane layouts (t innermost, 32B per (node,word)):
//   inpb/hs0b/zs0b : [node][w(4)][t(4)]   (NN*16 words)
//   hs1b           : [node][w(8)][t(4)]   (NN*32 words)
//   zs1b           : [node][w(2)][t(4)]   (NN*8  words)

// ---------------- Stage A: inp(t) = poisson(x, k1[t]) ----------------
__global__ __launch_bounds__(256) void k_pois_x(const float* __restrict__ x,
    uint64_t* __restrict__ bits, K8 K){
  int n = blockIdx.x, f = threadIdx.x;
  uint32_t i = (uint32_t)n*256u + (uint32_t)f;
  float xv = x[i];
  uint64_t pack[4];
  #pragma unroll
  for (int t=0;t<4;t++){
    bool b = (u01(jax_bits32(K.a[t],K.b[t], i, TOT)) <= xv);
    pack[t] = __ballot(b);
  }
  if ((f & 63)==0){
    uint64_t* dst = bits + ((size_t)n*4 + (f>>6))*4;
    #pragma unroll
    for (int t=0;t<4;t++) dst[t] = pack[t];
  }
}

// ---------------- Stage B: h0(t) fp32 gather (edge order) + poisson(h0,k2) ----------------
// 1-deep software pipeline: issue edge p+1's loads before accumulating edge p.
// fp32 add ORDER is unchanged (exactness vs reference preserved).
__global__ __launch_bounds__(256) void k_h0(const int* __restrict__ rp,
    const int* __restrict__ csrc, const float* __restrict__ cw,
    const uint64_t* __restrict__ inb, uint64_t* __restrict__ outb, K8 K){
  int n = blockIdx.x, f = threadIdx.x;
  int wi = f>>6, sh = f&63;
  int lo = rp[n], hi = rp[n+1];
  float a[4] = {0.f,0.f,0.f,0.f};
  if (lo < hi){
    int s = csrc[lo];
    float w = cw[lo];
    const uint64_t* bp = inb + ((size_t)s*4 + wi)*4;
    uint64_t b0=bp[0], b1=bp[1], b2=bp[2], b3=bp[3];
    for (int p=lo+1; p<hi; p++){
      int s2 = csrc[p];
      float w2 = cw[p];
      const uint64_t* bp2 = inb + ((size_t)s2*4 + wi)*4;
      uint64_t n0=bp2[0], n1=bp2[1], n2=bp2[2], n3=bp2[3];
      a[0] = __fadd_rn(a[0], ((b0>>sh)&1ull) ? w : 0.0f);
      a[1] = __fadd_rn(a[1], ((b1>>sh)&1ull) ? w : 0.0f);
      a[2] = __fadd_rn(a[2], ((b2>>sh)&1ull) ? w : 0.0f);
      a[3] = __fadd_rn(a[3], ((b3>>sh)&1ull) ? w : 0.0f);
      b0=n0; b1=n1; b2=n2; b3=n3; w=w2;
    }
    a[0] = __fadd_rn(a[0], ((b0>>sh)&1ull) ? w : 0.0f);
    a[1] = __fadd_rn(a[1], ((b1>>sh)&1ull) ? w : 0.0f);
    a[2] = __fadd_rn(a[2], ((b2>>sh)&1ull) ? w : 0.0f);
    a[3] = __fadd_rn(a[3], ((b3>>sh)&1ull) ? w : 0.0f);
  }
  uint32_t i = (uint32_t)n*256u + (uint32_t)f;
  uint64_t pack[4];
  #pragma unroll
  for (int t=0;t<4;t++){
    bool b = (u01(jax_bits32(K.a[t],K.b[t], i, TOT)) <= a[t]);
    pack[t] = __ballot(b);
  }
  if (sh==0){
    uint64_t* dst = outb + ((size_t)n*4 + wi)*4;
    #pragma unroll
    for (int t=0;t<4;t++) dst[t] = pack[t];
  }
}

// ---------------- Stage C: z0 = LIF_t(hs0 @ W1)  (K=256, M=256) ----------------
// 16 nodes/block (4 waves x 4-node group), 4 cols/thread (col = lane+64cc).
// Per q: 4 coalesced wr loads + 4 broadcast ds_read_b128 + 128 v_fma (1:16 ratio).
__global__ __launch_bounds__(256, 2) void k_z0(const uint64_t* __restrict__ inb,
    const float* __restrict__ W, uint64_t* __restrict__ outb){
  __shared__ __align__(16) float sp[16*64*4];    // [i(16)][k(64)][t(4)] 16KB
  int tid = threadIdx.x;
  int g = tid>>6, lane = tid&63;                 // wave = node group
  int n0 = blockIdx.x*16;
  float acc[4][4][4];                            // [t][i][cc]
  #pragma unroll
  for (int t=0;t<4;t++)
    #pragma unroll
    for (int i=0;i<4;i++)
      #pragma unroll
      for (int c=0;c<4;c++) acc[t][i][c]=0.0f;

  for (int kt=0; kt<4; kt++){
    #pragma unroll
    for (int rep=0; rep<4; rep++){
      int idx = rep*256 + tid;
      int i = idx>>6, k = idx&63;
      const uint64_t* bp = inb + (((size_t)(n0+i))*4 + kt)*4;
      uint64_t w0=bp[0], w1=bp[1], w2=bp[2], w3=bp[3];
      float4 f;
      f.x = ((w0>>k)&1ull) ? 1.0f : 0.0f;
      f.y = ((w1>>k)&1ull) ? 1.0f : 0.0f;
      f.z = ((w2>>k)&1ull) ? 1.0f : 0.0f;
      f.w = ((w3>>k)&1ull) ? 1.0f : 0.0f;
      *(float4*)&sp[(i*64+k)*4] = f;
    }
    __syncthreads();
    const float* Wrow = W + (size_t)(kt*64)*256 + lane;
    #pragma unroll 4
    for (int q=0;q<64;q++){
      const float* wb = Wrow + (size_t)q*256;
      float wr0 = wb[0], wr1 = wb[64], wr2 = wb[128], wr3 = wb[192];
      float4 s0 = *(const float4*)&sp[((g*4+0)*64+q)*4];
      float4 s1 = *(const float4*)&sp[((g*4+1)*64+q)*4];
      float4 s2 = *(const float4*)&sp[((g*4+2)*64+q)*4];
      float4 s3 = *(const float4*)&sp[((g*4+3)*64+q)*4];
      #define FMA4(ti, sv) \
        acc[ti][0][0]=__fmaf_rn(s0.sv,wr0,acc[ti][0][0]); acc[ti][0][1]=__fmaf_rn(s0.sv,wr1,acc[ti][0][1]); \
        acc[ti][0][2]=__fmaf_rn(s0.sv,wr2,acc[ti][0][2]); acc[ti][0][3]=__fmaf_rn(s0.sv,wr3,acc[ti][0][3]); \
        acc[ti][1][0]=__fmaf_rn(s1.sv,wr0,acc[ti][1][0]); acc[ti][1][1]=__fmaf_rn(s1.sv,wr1,acc[ti][1][1]); \
        acc[ti][1][2]=__fmaf_rn(s1.sv,wr2,acc[ti][1][2]); acc[ti][1][3]=__fmaf_rn(s1.sv,wr3,acc[ti][1][3]); \
        acc[ti][2][0]=__fmaf_rn(s2.sv,wr0,acc[ti][2][0]); acc[ti][2][1]=__fmaf_rn(s2.sv,wr1,acc[ti][2][1]); \
        acc[ti][2][2]=__fmaf_rn(s2.sv,wr2,acc[ti][2][2]); acc[ti][2][3]=__fmaf_rn(s2.sv,wr3,acc[ti][2][3]); \
        acc[ti][3][0]=__fmaf_rn(s3.sv,wr0,acc[ti][3][0]); acc[ti][3][1]=__fmaf_rn(s3.sv,wr1,acc[ti][3][1]); \
        acc[ti][3][2]=__fmaf_rn(s3.sv,wr2,acc[ti][3][2]); acc[ti][3][3]=__fmaf_rn(s3.sv,wr3,acc[ti][3][3]);
      FMA4(0, x) FMA4(1, y) FMA4(2, z) FMA4(3, w)
      #undef FMA4
    }
    __syncthreads();
  }

  #pragma unroll
  for (int i=0;i<4;i++){
    int node = n0 + g*4 + i;
    float v[4] = {0.f,0.f,0.f,0.f};
    #pragma unroll
    for (int t=0;t<4;t++){
      uint64_t b[4];
      #pragma unroll
      for (int c=0;c<4;c++){
        bool s = lif32(v[c], acc[t][i][c]);
        b[c] = __ballot(s);
      }
      if (lane==0){
        #pragma unroll
        for (int c=0;c<4;c++) outb[((size_t)node*4 + c)*4 + t] = b[c];
      }
    }
  }
}

// ---------------- Stage D: h1(t) gather over concat(zs0,hs0), LIF -> hs1 ----------------
// Same 1-deep software pipeline as k_h0; add order unchanged.
__global__ __launch_bounds__(512) void k_h1(const int* __restrict__ rp,
    const int* __restrict__ csrc, const float* __restrict__ cw,
    const uint64_t* __restrict__ zs0b, const uint64_t* __restrict__ hs0b,
    uint64_t* __restrict__ hs1b){
  int n = blockIdx.x, f = threadIdx.x;           // f in [0,512)
  int wi = f>>6, sh = f&63;
  const uint64_t* plane = (wi<4) ? zs0b : hs0b;
  int wo = wi & 3;
  int lo = rp[n], hi = rp[n+1];
  float a[4] = {0.f,0.f,0.f,0.f};
  if (lo < hi){
    int s = csrc[lo];
    float w = cw[lo];
    const uint64_t* bp = plane + ((size_t)s*4 + wo)*4;
    uint64_t b0=bp[0], b1=bp[1], b2=bp[2], b3=bp[3];
    for (int p=lo+1; p<hi; p++){
      int s2 = csrc[p];
      float w2 = cw[p];
      const uint64_t* bp2 = plane + ((size_t)s2*4 + wo)*4;
      uint64_t n0=bp2[0], n1=bp2[1], n2=bp2[2], n3=bp2[3];
      a[0] = __fadd_rn(a[0], ((b0>>sh)&1ull) ? w : 0.0f);
      a[1] = __fadd_rn(a[1], ((b1>>sh)&1ull) ? w : 0.0f);
      a[2] = __fadd_rn(a[2], ((b2>>sh)&1ull) ? w : 0.0f);
      a[3] = __fadd_rn(a[3], ((b3>>sh)&1ull) ? w : 0.0f);
      b0=n0; b1=n1; b2=n2; b3=n3; w=w2;
    }
    a[0] = __fadd_rn(a[0], ((b0>>sh)&1ull) ? w : 0.0f);
    a[1] = __fadd_rn(a[1], ((b1>>sh)&1ull) ? w : 0.0f);
    a[2] = __fadd_rn(a[2], ((b2>>sh)&1ull) ? w : 0.0f);
    a[3] = __fadd_rn(a[3], ((b3>>sh)&1ull) ? w : 0.0f);
  }
  float v = 0.0f;
  uint64_t pack[4];
  #pragma unroll
  for (int t=0;t<4;t++){
    bool s = lif32(v, a[t]);
    pack[t] = __ballot(s);
  }
  if (sh==0){
    uint64_t* dst = hs1b + ((size_t)n*8 + wi)*4;
    #pragma unroll
    for (int t=0;t<4;t++) dst[t] = pack[t];
  }
}

// ---------------- Stage E: z1 = LIF_t(hs1 @ W2)  (K=512, M=128) ----------------
// v4: k_z0's proven code shape at K=512. Half-wave 4-col mapping
// (col = (lane&31)+32cc, round-10-verified packing), 256 threads,
// 8 half-wave groups x 4 nodes = 32 nodes/block. Per q: 4 batched
// 2-addr broadcast LDS reads + 4 W loads + 64 FMA (1:16), unroll 4.
// Per-(node,col,t) FMA order over (kt,q) unchanged -> bit-exact.
// Tail block: stores guarded by node<NN; staging reads stay in workspace
// (zs1b follows hs1b); validity boundary (node 50000) falls on a wave
// boundary so no ballot mixes valid and invalid nodes.
__global__ __launch_bounds__(256, 2) void k_z1(const uint64_t* __restrict__ inb,
    const float* __restrict__ W, uint64_t* __restrict__ outb){
  __shared__ __align__(16) float sp[32*64*4];    // [i(32)][k(64)][t(4)] 32KB
  int tid = threadIdx.x;
  int wv = tid>>6, lane = tid&63;
  int half = lane>>5, cl = lane&31;
  int gi = wv*2 + half;                          // node group of this half-wave, [0,8)
  int n0 = blockIdx.x*32;
  float acc[4][4][4];                            // [t][i][cc]
  #pragma unroll
  for (int t=0;t<4;t++)
    #pragma unroll
    for (int i=0;i<4;i++)
      #pragma unroll
      for (int c=0;c<4;c++) acc[t][i][c]=0.0f;

  for (int kt=0; kt<8; kt++){
    #pragma unroll
    for (int rep=0; rep<8; rep++){
      int idx = rep*256 + tid;                   // 0..2047
      int i = idx>>6, k = idx&63;                // i in [0,32)
      const uint64_t* bp = inb + (((size_t)(n0+i))*8 + kt)*4;
      uint64_t w0=bp[0], w1=bp[1], w2=bp[2], w3=bp[3];
      float4 f;
      f.x = ((w0>>k)&1ull) ? 1.0f : 0.0f;
      f.y = ((w1>>k)&1ull) ? 1.0f : 0.0f;
      f.z = ((w2>>k)&1ull) ? 1.0f : 0.0f;
      f.w = ((w3>>k)&1ull) ? 1.0f : 0.0f;
      *(float4*)&sp[(i*64+k)*4] = f;
    }
    __syncthreads();
    const float* Wrow = W + (size_t)(kt*64)*128 + cl;
    #pragma unroll 4
    for (int q=0;q<64;q++){
      const float* wb = Wrow + (size_t)q*128;
      float wr0 = wb[0], wr1 = wb[32], wr2 = wb[64], wr3 = wb[96];
      float4 s0 = *(const float4*)&sp[((gi*4+0)*64+q)*4];
      float4 s1 = *(const float4*)&sp[((gi*4+1)*64+q)*4];
      float4 s2 = *(const float4*)&sp[((gi*4+2)*64+q)*4];
      float4 s3 = *(const float4*)&sp[((gi*4+3)*64+q)*4];
      #define FMA4(ti, sv) \
        acc[ti][0][0]=__fmaf_rn(s0.sv,wr0,acc[ti][0][0]); acc[ti][0][1]=__fmaf_rn(s0.sv,wr1,acc[ti][0][1]); \
        acc[ti][0][2]=__fmaf_rn(s0.sv,wr2,acc[ti][0][2]); acc[ti][0][3]=__fmaf_rn(s0.sv,wr3,acc[ti][0][3]); \
        acc[ti][1][0]=__fmaf_rn(s1.sv,wr0,acc[ti][1][0]); acc[ti][1][1]=__fmaf_rn(s1.sv,wr1,acc[ti][1][1]); \
        acc[ti][1][2]=__fmaf_rn(s1.sv,wr2,acc[ti][1][2]); acc[ti][1][3]=__fmaf_rn(s1.sv,wr3,acc[ti][1][3]); \
        acc[ti][2][0]=__fmaf_rn(s2.sv,wr0,acc[ti][2][0]); acc[ti][2][1]=__fmaf_rn(s2.sv,wr1,acc[ti][2][1]); \
        acc[ti][2][2]=__fmaf_rn(s2.sv,wr2,acc[ti][2][2]); acc[ti][2][3]=__fmaf_rn(s2.sv,wr3,acc[ti][2][3]); \
        acc[ti][3][0]=__fmaf_rn(s3.sv,wr0,acc[ti][3][0]); acc[ti][3][1]=__fmaf_rn(s3.sv,wr1,acc[ti][3][1]); \
        acc[ti][3][2]=__fmaf_rn(s3.sv,wr2,acc[ti][3][2]); acc[ti][3][3]=__fmaf_rn(s3.sv,wr3,acc[ti][3][3]);
      FMA4(0, x) FMA4(1, y) FMA4(2, z) FMA4(3, w)
      #undef FMA4
    }
    __syncthreads();
  }

  #pragma unroll
  for (int i=0;i<4;i++){
    int node = n0 + gi*4 + i;
    float v[4] = {0.f,0.f,0.f,0.f};
    #pragma unroll
    for (int t=0;t<4;t++){
      uint64_t b0,b1,b2,b3;
      { bool s = lif32(v[0], acc[t][i][0]); b0 = __ballot(s); }
      { bool s = lif32(v[1], acc[t][i][1]); b1 = __ballot(s); }
      { bool s = lif32(v[2], acc[t][i][2]); b2 = __ballot(s); }
      { bool s = lif32(v[3], acc[t][i][3]); b3 = __ballot(s); }
      if (cl==0 && node < NN){
        uint64_t m0, m1;
        if (half==0){
          m0 = (b0 & 0xffffffffull) | ((b1 & 0xffffffffull)<<32);
          m1 = (b2 & 0xffffffffull) | ((b3 & 0xffffffffull)<<32);
        } else {
          m0 = (b0>>32) | ((b1>>32)<<32);
          m1 = (b2>>32) | ((b3>>32)<<32);
        }
        outb[((size_t)node*2 + 0)*4 + t] = m0;
        outb[((size_t)node*2 + 1)*4 + t] = m1;
      }
    }
  }
}

// ---------------- Stage F: decoder + y + sigmoid ----------------
__global__ __launch_bounds__(128) void k_dec_y(const int* __restrict__ ns,
    const int* __restrict__ nt, const uint64_t* __restrict__ zs1b,
    const float* __restrict__ Wd, const float* __restrict__ bd,
    const float* __restrict__ wrec, float* __restrict__ out){
  int i = blockIdx.x;
  int tid = threadIdx.x;
  int row = tid>>6, j = tid&63;
  int node = row ? nt[i] : ns[i];
  float bdj = bd[j];
  double wrecj = (double)wrec[j];
  __shared__ uint64_t sw[2];

  uint32_t wlo[2][4], whi[2][4];
  const uint64_t* bp = zs1b + (size_t)node*8;
  #pragma unroll
  for (int g=0;g<2;g++)
    #pragma unroll
    for (int t=0;t<4;t++){
      uint64_t w8 = bp[g*4+t];
      wlo[g][t] = (uint32_t)w8;
      whi[g][t] = (uint32_t)(w8>>32);
      FORCE_V(wlo[g][t]); FORCE_V(whi[g][t]);
    }

  float acc[4] = {0.f,0.f,0.f,0.f};
  #pragma unroll
  for (int g=0;g<2;g++){
    #pragma unroll
    for (int h=0;h<2;h++){
      #pragma unroll
      for (int c=0;c<2;c++){
        float wr[16];
        #pragma unroll
        for (int q=0;q<16;q++) wr[q] = Wd[(size_t)(g*64+h*32+c*16+q)*64 + j];
        #pragma unroll
        for (int q=0;q<16;q++){
          int b = c*16+q;
          #pragma unroll
          for (int t=0;t<4;t++){
            uint32_t wv = h ? whi[g][t] : wlo[g][t];
            acc[t] = __fadd_rn(acc[t], bitmaskf(wv, b, wr[q]));
          }
        }
      }
    }
  }

  float v = 0.0f;
  double ysum = 0.0;
  #pragma unroll
  for (int t=0;t<4;t++){
    float a = __fadd_rn(acc[t], bdj);
    bool s = lif32(v, a);
    uint64_t bw = __ballot(s);
    if (j==0) sw[row] = bw;
    __syncthreads();
    uint64_t m = sw[0] & sw[1];
    __syncthreads();
    double term = ((m>>j)&1ull) ? wrecj : 0.0;
    #pragma unroll
    for (int off=1; off<64; off<<=1) term += shflxor_d(term, off);
    ysum += term;
  }
  if (tid==0) out[i] = (float)(1.0/(1.0 + exp(-0.25*ysum)));
}

// ---------------- Launcher ----------------
extern "C" void kernel_launch(void* const* d_in, const int* in_sizes, int n_in,
                              void* d_out, int out_size, void* d_ws, size_t ws_size,
                              hipStream_t stream) {
  const float* x    = (const float*)d_in[0];
  const float* W1   = (const float*)d_in[1];
  const float* W2   = (const float*)d_in[2];
  const float* Wd   = (const float*)d_in[3];
  const float* bd   = (const float*)d_in[4];
  const float* wrec = (const float*)d_in[5];
  const float* ew   = (const float*)d_in[6];
  const int* esrc   = (const int*)d_in[7];
  const int* edst   = (const int*)d_in[8];
  const int* ns     = (const int*)d_in[9];
  const int* nt     = (const int*)d_in[10];
  float* out = (float*)d_out;
  (void)in_sizes; (void)n_in; (void)out_size; (void)ws_size;

  // workspace layout (~41 MB)
  char* p = (char*)d_ws;
  uint64_t* inpb = (uint64_t*)p; p += (size_t)NN*16*8;
  uint64_t* hs0b = (uint64_t*)p; p += (size_t)NN*16*8;
  uint64_t* zs0b = (uint64_t*)p; p += (size_t)NN*16*8;
  uint64_t* hs1b = (uint64_t*)p; p += (size_t)NN*32*8;
  uint64_t* zs1b = (uint64_t*)p; p += (size_t)NN*8*8;
  int*   eidx = (int*)p;   p += (size_t)NE*4;
  int*   csrc = (int*)p;   p += (size_t)NE*4;
  float* cw   = (float*)p; p += (size_t)NE*4;
  int*   cnt  = (int*)p;   p += (size_t)(NN+2)*4;
  int*   rp   = (int*)p;   p += (size_t)(NN+2)*4;
  int*   cur  = (int*)p;   p += (size_t)(NN+2)*4;

  // host-side key chain: key=(0,42); kt=fold_in(key,t); k1,k2=split(kt)
  K8 K1, K2;
  for (int t=0;t<4;t++){
    uint32_t kt0,kt1;
    tf2x32(0u, 42u, 0u, (uint32_t)t, kt0, kt1);
#if JAX_PARTITIONABLE
    tf2x32(kt0, kt1, 0u, 0u, K1.a[t], K1.b[t]);
    tf2x32(kt0, kt1, 0u, 1u, K2.a[t], K2.b[t]);
#else
    uint32_t A0,B0,A1,B1;
    tf2x32(kt0, kt1, 0u, 2u, A0, B0);
    tf2x32(kt0, kt1, 1u, 3u, A1, B1);
    K1.a[t]=A0; K1.b[t]=A1; K2.a[t]=B0; K2.b[t]=B1;
#endif
  }

  // CSR build (deterministic via per-row sort by edge id)
  hipMemsetAsync(cnt, 0, (size_t)NN*4, stream);
  k_hist   <<<(NE+255)/256, 256, 0, stream>>>(edst, cnt);
  k_scan   <<<1, 1024, 0, stream>>>(cnt, rp, cur);
  k_scatter<<<(NE+255)/256, 256, 0, stream>>>(edst, cur, eidx);
  k_sortrow<<<(NN+255)/256, 256, 0, stream>>>(rp, eidx, esrc, ew, csrc, cw);

  // stage-major pipeline, all T=4 per kernel, LIF state in registers (fp32)
  k_pois_x<<<NN, 256, 0, stream>>>(x, inpb, K1);
  k_h0    <<<NN, 256, 0, stream>>>(rp, csrc, cw, inpb, hs0b, K2);
  k_z0    <<<NN/16, 256, 0, stream>>>(hs0b, W1, zs0b);
  k_h1    <<<NN, 512, 0, stream>>>(rp, csrc, cw, zs0b, hs0b, hs1b);
  k_z1    <<<(NN+31)/32, 256, 0, stream>>>(hs1b, W2, zs1b);
  k_dec_y <<<NL, 128, 0, stream>>>(ns, nt, zs1b, Wd, bd, wrec, out);
}

// Round 21
// 1595.688 us; speedup vs baseline: 1.1440x; 1.0016x over previous
//
#include <hip/hip_runtime.h>
#include <stdint.h>
#include <math.h>

// Problem constants
#define NN    50000       // N_NODES
#define NE    400000      // N_EDGES
#define NL    50000       // N_LINKS
#define TOT   12800000    // NN*256

#define JAX_PARTITIONABLE 1

struct K8 { uint32_t a[4]; uint32_t b[4]; };

// ---------------- Threefry-2x32 (20 rounds) ----------------
__host__ __device__ inline uint32_t rotl32(uint32_t x, int r){ return (x<<r)|(x>>(32-r)); }

__host__ __device__ inline void tf2x32(uint32_t k0, uint32_t k1, uint32_t x0, uint32_t x1,
                                       uint32_t &o0, uint32_t &o1) {
  uint32_t k2 = k0 ^ k1 ^ 0x1BD11BDAu;
  x0 += k0; x1 += k1;
#define TFR(r) { x0 += x1; x1 = rotl32(x1,(r)); x1 ^= x0; }
  TFR(13) TFR(15) TFR(26) TFR(6)
  x0 += k1; x1 += k2 + 1u;
  TFR(17) TFR(29) TFR(16) TFR(24)
  x0 += k2; x1 += k0 + 2u;
  TFR(13) TFR(15) TFR(26) TFR(6)
  x0 += k0; x1 += k1 + 3u;
  TFR(17) TFR(29) TFR(16) TFR(24)
  x0 += k1; x1 += k2 + 4u;
  TFR(13) TFR(15) TFR(26) TFR(6)
  x0 += k2; x1 += k0 + 5u;
#undef TFR
  o0 = x0; o1 = x1;
}

__device__ inline float u01(uint32_t b){
  return __uint_as_float((b>>9) | 0x3f800000u) - 1.0f;   // [1,2) - 1, exact
}

__device__ inline uint32_t jax_bits32(uint32_t ka, uint32_t kb, uint32_t i, uint32_t total){
#if JAX_PARTITIONABLE
  uint32_t o0,o1; tf2x32(ka,kb, 0u, i, o0,o1); return o0^o1;
#else
  uint32_t h = total>>1; uint32_t o0,o1;
  if (i < h){ tf2x32(ka,kb, i, i+h, o0,o1); return o0; }
  else      { tf2x32(ka,kb, i-h, i, o0,o1); return o1; }
#endif
}

__device__ inline double shflxor_d(double x, int m){
  union { double d; int i[2]; } u; u.d = x;
  u.i[0] = __shfl_xor(u.i[0], m, 64);
  u.i[1] = __shfl_xor(u.i[1], m, 64);
  return u.d;
}

// exact fp32 LIF step: v = fl(fl(v*0.5)+a); d = fl(v-0.2); s=(d>=0); v = s?d:v
__device__ inline bool lif32(float &v, float a){
  v = __fadd_rn(__fmul_rn(v, 0.5f), a);
  float d = __fsub_rn(v, 0.2f);
  bool s = (d >= 0.0f);
  v = s ? d : v;
  return s;
}

// force a value to live in a VGPR
#define FORCE_V(x) asm volatile("" : "+v"(x))

// wr if bit b of w set, else +0.0f — used in decoder (small)
__device__ inline float bitmaskf(uint32_t w, int b, float wr){
#if __has_builtin(__builtin_amdgcn_sbfe)
  int m = __builtin_amdgcn_sbfe((int)w, b, 1);
#else
  int m = ((int)(w << (31-b))) >> 31;
#endif
  return __int_as_float(__float_as_int(wr) & m);
}

// ---------------- CSR build (by dst), deterministic edge order ----------------
__global__ __launch_bounds__(256) void k_hist(const int* __restrict__ dst, int* __restrict__ cnt){
  int e = blockIdx.x*256 + threadIdx.x;
  if (e < NE) atomicAdd(&cnt[dst[e]], 1);
}

// wave-shuffle scan: 3 barriers per 1024-chunk (was ~20)
__global__ __launch_bounds__(1024) void k_scan(const int* __restrict__ cnt,
    int* __restrict__ rp, int* __restrict__ cur){
  __shared__ int ws[16];
  __shared__ int wp[17];
  int tid = threadIdx.x;
  int lane = tid & 63, wid = tid >> 6;
  int carry = 0;
  for (int base=0; base<NN; base+=1024){
    int v = (base+tid < NN) ? cnt[base+tid] : 0;
    int x = v;
    #pragma unroll
    for (int off=1; off<64; off<<=1){
      int u = __shfl_up(x, off, 64);
      if (lane >= off) x += u;
    }
    if (lane==63) ws[wid] = x;
    __syncthreads();
    if (wid==0){
      int s = (lane<16) ? ws[lane] : 0;
      #pragma unroll
      for (int off=1; off<16; off<<=1){
        int u = __shfl_up(s, off, 64);
        if (lane >= off) s += u;
      }
      if (lane<16) wp[lane+1] = s;
      if (lane==0) wp[0] = 0;
    }
    __syncthreads();
    int excl = x - v + wp[wid] + carry;
    if (base+tid < NN){ rp[base+tid] = excl; cur[base+tid] = excl; }
    carry += wp[16];
    __syncthreads();
  }
  if (tid==0) rp[NN] = NE;
}

__global__ __launch_bounds__(256) void k_scatter(const int* __restrict__ dst,
    int* __restrict__ cur, int* __restrict__ eidx){
  int e = blockIdx.x*256 + threadIdx.x;
  if (e < NE){ int p = atomicAdd(&cur[dst[e]], 1); eidx[p] = e; }
}

__global__ __launch_bounds__(256) void k_sortrow(const int* __restrict__ rp,
    int* __restrict__ eidx, const int* __restrict__ esrc, const float* __restrict__ ew,
    int* __restrict__ csrc, float* __restrict__ cw){
  int n = blockIdx.x*256 + threadIdx.x;
  if (n >= NN) return;
  int lo = rp[n], hi = rp[n+1];
  for (int a=lo+1; a<hi; a++){
    int k = eidx[a]; int b = a-1;
    while (b>=lo && eidx[b]>k){ eidx[b+1]=eidx[b]; b--; }
    eidx[b+1] = k;
  }
  for (int p=lo; p<hi; p++){ int e = eidx[p]; csrc[p] = esrc[e]; cw[p] = ew[e]; }
}

// Plane layouts (t innermost, 32B per (node,word)):
//   inpb/hs0b/zs0b : [node][w(4)][t(4)]   (NN*16 words)
//   hs1b           : [node][w(8)][t(4)]   (NN*32 words)
//   zs1b           : [node][w(2)][t(4)]   (NN*8  words)

// ---------------- Stage A: inp(t) = poisson(x, k1[t]) ----------------
__global__ __launch_bounds__(256) void k_pois_x(const float* __restrict__ x,
    uint64_t* __restrict__ bits, K8 K){
  int n = blockIdx.x, f = threadIdx.x;
  uint32_t i = (uint32_t)n*256u + (uint32_t)f;
  float xv = x[i];
  uint64_t pack[4];
  #pragma unroll
  for (int t=0;t<4;t++){
    bool b = (u01(jax_bits32(K.a[t],K.b[t], i, TOT)) <= xv);
    pack[t] = __ballot(b);
  }
  if ((f & 63)==0){
    uint64_t* dst = bits + ((size_t)n*4 + (f>>6))*4;
    #pragma unroll
    for (int t=0;t<4;t++) dst[t] = pack[t];
  }
}

// ---------------- Stage B: h0(t) fp32 gather (edge order) + poisson(h0,k2) ----------------
// 1-deep software pipeline: issue edge p+1's loads before accumulating edge p.
// fp32 add ORDER is unchanged (exactness vs reference preserved).
__global__ __launch_bounds__(256) void k_h0(const int* __restrict__ rp,
    const int* __restrict__ csrc, const float* __restrict__ cw,
    const uint64_t* __restrict__ inb, uint64_t* __restrict__ outb, K8 K){
  int n = blockIdx.x, f = threadIdx.x;
  int wi = f>>6, sh = f&63;
  int lo = rp[n], hi = rp[n+1];
  float a[4] = {0.f,0.f,0.f,0.f};
  if (lo < hi){
    int s = csrc[lo];
    float w = cw[lo];
    const uint64_t* bp = inb + ((size_t)s*4 + wi)*4;
    uint64_t b0=bp[0], b1=bp[1], b2=bp[2], b3=bp[3];
    for (int p=lo+1; p<hi; p++){
      int s2 = csrc[p];
      float w2 = cw[p];
      const uint64_t* bp2 = inb + ((size_t)s2*4 + wi)*4;
      uint64_t n0=bp2[0], n1=bp2[1], n2=bp2[2], n3=bp2[3];
      a[0] = __fadd_rn(a[0], ((b0>>sh)&1ull) ? w : 0.0f);
      a[1] = __fadd_rn(a[1], ((b1>>sh)&1ull) ? w : 0.0f);
      a[2] = __fadd_rn(a[2], ((b2>>sh)&1ull) ? w : 0.0f);
      a[3] = __fadd_rn(a[3], ((b3>>sh)&1ull) ? w : 0.0f);
      b0=n0; b1=n1; b2=n2; b3=n3; w=w2;
    }
    a[0] = __fadd_rn(a[0], ((b0>>sh)&1ull) ? w : 0.0f);
    a[1] = __fadd_rn(a[1], ((b1>>sh)&1ull) ? w : 0.0f);
    a[2] = __fadd_rn(a[2], ((b2>>sh)&1ull) ? w : 0.0f);
    a[3] = __fadd_rn(a[3], ((b3>>sh)&1ull) ? w : 0.0f);
  }
  uint32_t i = (uint32_t)n*256u + (uint32_t)f;
  uint64_t pack[4];
  #pragma unroll
  for (int t=0;t<4;t++){
    bool b = (u01(jax_bits32(K.a[t],K.b[t], i, TOT)) <= a[t]);
    pack[t] = __ballot(b);
  }
  if (sh==0){
    uint64_t* dst = outb + ((size_t)n*4 + wi)*4;
    #pragma unroll
    for (int t=0;t<4;t++) dst[t] = pack[t];
  }
}

// ---------------- Stage C: z0 = LIF_t(hs0 @ W1)  (K=256, M=256) ----------------
// 16 nodes/block (4 waves x 4-node group), 4 cols/thread (col = lane+64cc).
// Per q: 4 coalesced wr loads + 4 broadcast ds_read_b128 + 128 v_fma (1:16 ratio).
__global__ __launch_bounds__(256, 2) void k_z0(const uint64_t* __restrict__ inb,
    const float* __restrict__ W, uint64_t* __restrict__ outb){
  __shared__ __align__(16) float sp[16*64*4];    // [i(16)][k(64)][t(4)] 16KB
  int tid = threadIdx.x;
  int g = tid>>6, lane = tid&63;                 // wave = node group
  int n0 = blockIdx.x*16;
  float acc[4][4][4];                            // [t][i][cc]
  #pragma unroll
  for (int t=0;t<4;t++)
    #pragma unroll
    for (int i=0;i<4;i++)
      #pragma unroll
      for (int c=0;c<4;c++) acc[t][i][c]=0.0f;

  for (int kt=0; kt<4; kt++){
    #pragma unroll
    for (int rep=0; rep<4; rep++){
      int idx = rep*256 + tid;
      int i = idx>>6, k = idx&63;
      const uint64_t* bp = inb + (((size_t)(n0+i))*4 + kt)*4;
      uint64_t w0=bp[0], w1=bp[1], w2=bp[2], w3=bp[3];
      float4 f;
      f.x = ((w0>>k)&1ull) ? 1.0f : 0.0f;
      f.y = ((w1>>k)&1ull) ? 1.0f : 0.0f;
      f.z = ((w2>>k)&1ull) ? 1.0f : 0.0f;
      f.w = ((w3>>k)&1ull) ? 1.0f : 0.0f;
      *(float4*)&sp[(i*64+k)*4] = f;
    }
    __syncthreads();
    const float* Wrow = W + (size_t)(kt*64)*256 + lane;
    #pragma unroll 4
    for (int q=0;q<64;q++){
      const float* wb = Wrow + (size_t)q*256;
      float wr0 = wb[0], wr1 = wb[64], wr2 = wb[128], wr3 = wb[192];
      float4 s0 = *(const float4*)&sp[((g*4+0)*64+q)*4];
      float4 s1 = *(const float4*)&sp[((g*4+1)*64+q)*4];
      float4 s2 = *(const float4*)&sp[((g*4+2)*64+q)*4];
      float4 s3 = *(const float4*)&sp[((g*4+3)*64+q)*4];
      #define FMA4(ti, sv) \
        acc[ti][0][0]=__fmaf_rn(s0.sv,wr0,acc[ti][0][0]); acc[ti][0][1]=__fmaf_rn(s0.sv,wr1,acc[ti][0][1]); \
        acc[ti][0][2]=__fmaf_rn(s0.sv,wr2,acc[ti][0][2]); acc[ti][0][3]=__fmaf_rn(s0.sv,wr3,acc[ti][0][3]); \
        acc[ti][1][0]=__fmaf_rn(s1.sv,wr0,acc[ti][1][0]); acc[ti][1][1]=__fmaf_rn(s1.sv,wr1,acc[ti][1][1]); \
        acc[ti][1][2]=__fmaf_rn(s1.sv,wr2,acc[ti][1][2]); acc[ti][1][3]=__fmaf_rn(s1.sv,wr3,acc[ti][1][3]); \
        acc[ti][2][0]=__fmaf_rn(s2.sv,wr0,acc[ti][2][0]); acc[ti][2][1]=__fmaf_rn(s2.sv,wr1,acc[ti][2][1]); \
        acc[ti][2][2]=__fmaf_rn(s2.sv,wr2,acc[ti][2][2]); acc[ti][2][3]=__fmaf_rn(s2.sv,wr3,acc[ti][2][3]); \
        acc[ti][3][0]=__fmaf_rn(s3.sv,wr0,acc[ti][3][0]); acc[ti][3][1]=__fmaf_rn(s3.sv,wr1,acc[ti][3][1]); \
        acc[ti][3][2]=__fmaf_rn(s3.sv,wr2,acc[ti][3][2]); acc[ti][3][3]=__fmaf_rn(s3.sv,wr3,acc[ti][3][3]);
      FMA4(0, x) FMA4(1, y) FMA4(2, z) FMA4(3, w)
      #undef FMA4
    }
    __syncthreads();
  }

  #pragma unroll
  for (int i=0;i<4;i++){
    int node = n0 + g*4 + i;
    float v[4] = {0.f,0.f,0.f,0.f};
    #pragma unroll
    for (int t=0;t<4;t++){
      uint64_t b[4];
      #pragma unroll
      for (int c=0;c<4;c++){
        bool s = lif32(v[c], acc[t][i][c]);
        b[c] = __ballot(s);
      }
      if (lane==0){
        #pragma unroll
        for (int c=0;c<4;c++) outb[((size_t)node*4 + c)*4 + t] = b[c];
      }
    }
  }
}

// ---------------- Stage D: h1(t) gather over concat(zs0,hs0), LIF -> hs1 ----------------
// Same 1-deep software pipeline as k_h0; add order unchanged.
__global__ __launch_bounds__(512) void k_h1(const int* __restrict__ rp,
    const int* __restrict__ csrc, const float* __restrict__ cw,
    const uint64_t* __restrict__ zs0b, const uint64_t* __restrict__ hs0b,
    uint64_t* __restrict__ hs1b){
  int n = blockIdx.x, f = threadIdx.x;           // f in [0,512)
  int wi = f>>6, sh = f&63;
  const uint64_t* plane = (wi<4) ? zs0b : hs0b;
  int wo = wi & 3;
  int lo = rp[n], hi = rp[n+1];
  float a[4] = {0.f,0.f,0.f,0.f};
  if (lo < hi){
    int s = csrc[lo];
    float w = cw[lo];
    const uint64_t* bp = plane + ((size_t)s*4 + wo)*4;
    uint64_t b0=bp[0], b1=bp[1], b2=bp[2], b3=bp[3];
    for (int p=lo+1; p<hi; p++){
      int s2 = csrc[p];
      float w2 = cw[p];
      const uint64_t* bp2 = plane + ((size_t)s2*4 + wo)*4;
      uint64_t n0=bp2[0], n1=bp2[1], n2=bp2[2], n3=bp2[3];
      a[0] = __fadd_rn(a[0], ((b0>>sh)&1ull) ? w : 0.0f);
      a[1] = __fadd_rn(a[1], ((b1>>sh)&1ull) ? w : 0.0f);
      a[2] = __fadd_rn(a[2], ((b2>>sh)&1ull) ? w : 0.0f);
      a[3] = __fadd_rn(a[3], ((b3>>sh)&1ull) ? w : 0.0f);
      b0=n0; b1=n1; b2=n2; b3=n3; w=w2;
    }
    a[0] = __fadd_rn(a[0], ((b0>>sh)&1ull) ? w : 0.0f);
    a[1] = __fadd_rn(a[1], ((b1>>sh)&1ull) ? w : 0.0f);
    a[2] = __fadd_rn(a[2], ((b2>>sh)&1ull) ? w : 0.0f);
    a[3] = __fadd_rn(a[3], ((b3>>sh)&1ull) ? w : 0.0f);
  }
  float v = 0.0f;
  uint64_t pack[4];
  #pragma unroll
  for (int t=0;t<4;t++){
    bool s = lif32(v, a[t]);
    pack[t] = __ballot(s);
  }
  if (sh==0){
    uint64_t* dst = hs1b + ((size_t)n*8 + wi)*4;
    #pragma unroll
    for (int t=0;t<4;t++) dst[t] = pack[t];
  }
}

// ---------------- Stage E: z1 = LIF_t(hs1 @ W2)  (K=512, M=128) ----------------
// v5 = v2 (measured 385us, occ 38.7%) with deeper load batching: unroll 8.
// 16 nodes/block (4 waves x 4-node group), 256 threads, 2 cols/thread
// (col = lane + 64*c). Full-wave broadcast ds_read. Per-(node,col,t) FMA
// order over (kt,q) identical to v2 -> bit-exact (unroll preserves each
// acc element's sequential chain).
__global__ __launch_bounds__(256, 2) void k_z1(const uint64_t* __restrict__ inb,
    const float* __restrict__ W, uint64_t* __restrict__ outb){
  __shared__ __align__(16) float sp[16*64*4];    // [i(16)][k(64)][t(4)] 16KB
  int tid = threadIdx.x;
  int g = tid>>6, lane = tid&63;                 // wave = node group
  int n0 = blockIdx.x*16;
  float acc[4][4][2];                            // [t][i][c]
  #pragma unroll
  for (int t=0;t<4;t++)
    #pragma unroll
    for (int i=0;i<4;i++){ acc[t][i][0]=0.0f; acc[t][i][1]=0.0f; }

  for (int kt=0; kt<8; kt++){
    #pragma unroll
    for (int rep=0; rep<4; rep++){
      int idx = rep*256 + tid;
      int i = idx>>6, k = idx&63;
      const uint64_t* bp = inb + (((size_t)(n0+i))*8 + kt)*4;
      uint64_t w0=bp[0], w1=bp[1], w2=bp[2], w3=bp[3];
      float4 f;
      f.x = ((w0>>k)&1ull) ? 1.0f : 0.0f;
      f.y = ((w1>>k)&1ull) ? 1.0f : 0.0f;
      f.z = ((w2>>k)&1ull) ? 1.0f : 0.0f;
      f.w = ((w3>>k)&1ull) ? 1.0f : 0.0f;
      *(float4*)&sp[(i*64+k)*4] = f;
    }
    __syncthreads();
    const float* Wrow = W + (size_t)(kt*64)*128 + lane;
    #pragma unroll 8
    for (int q=0;q<64;q++){
      const float* wb = Wrow + (size_t)q*128;
      float wr0 = wb[0], wr1 = wb[64];
      float4 s0 = *(const float4*)&sp[((g*4+0)*64+q)*4];
      float4 s1 = *(const float4*)&sp[((g*4+1)*64+q)*4];
      float4 s2 = *(const float4*)&sp[((g*4+2)*64+q)*4];
      float4 s3 = *(const float4*)&sp[((g*4+3)*64+q)*4];
      #define FMA2(ti, sv) \
        acc[ti][0][0]=__fmaf_rn(s0.sv,wr0,acc[ti][0][0]); acc[ti][0][1]=__fmaf_rn(s0.sv,wr1,acc[ti][0][1]); \
        acc[ti][1][0]=__fmaf_rn(s1.sv,wr0,acc[ti][1][0]); acc[ti][1][1]=__fmaf_rn(s1.sv,wr1,acc[ti][1][1]); \
        acc[ti][2][0]=__fmaf_rn(s2.sv,wr0,acc[ti][2][0]); acc[ti][2][1]=__fmaf_rn(s2.sv,wr1,acc[ti][2][1]); \
        acc[ti][3][0]=__fmaf_rn(s3.sv,wr0,acc[ti][3][0]); acc[ti][3][1]=__fmaf_rn(s3.sv,wr1,acc[ti][3][1]);
      FMA2(0, x) FMA2(1, y) FMA2(2, z) FMA2(3, w)
      #undef FMA2
    }
    __syncthreads();
  }

  #pragma unroll
  for (int i=0;i<4;i++){
    int node = n0 + g*4 + i;
    float v0 = 0.0f, v1 = 0.0f;
    #pragma unroll
    for (int t=0;t<4;t++){
      uint64_t b0, b1;
      { bool s = lif32(v0, acc[t][i][0]); b0 = __ballot(s); }   // cols 0..63
      { bool s = lif32(v1, acc[t][i][1]); b1 = __ballot(s); }   // cols 64..127
      if (lane==0){
        outb[((size_t)node*2 + 0)*4 + t] = b0;
        outb[((size_t)node*2 + 1)*4 + t] = b1;
      }
    }
  }
}

// ---------------- Stage F: decoder + y + sigmoid ----------------
__global__ __launch_bounds__(128) void k_dec_y(const int* __restrict__ ns,
    const int* __restrict__ nt, const uint64_t* __restrict__ zs1b,
    const float* __restrict__ Wd, const float* __restrict__ bd,
    const float* __restrict__ wrec, float* __restrict__ out){
  int i = blockIdx.x;
  int tid = threadIdx.x;
  int row = tid>>6, j = tid&63;
  int node = row ? nt[i] : ns[i];
  float bdj = bd[j];
  double wrecj = (double)wrec[j];
  __shared__ uint64_t sw[2];

  uint32_t wlo[2][4], whi[2][4];
  const uint64_t* bp = zs1b + (size_t)node*8;
  #pragma unroll
  for (int g=0;g<2;g++)
    #pragma unroll
    for (int t=0;t<4;t++){
      uint64_t w8 = bp[g*4+t];
      wlo[g][t] = (uint32_t)w8;
      whi[g][t] = (uint32_t)(w8>>32);
      FORCE_V(wlo[g][t]); FORCE_V(whi[g][t]);
    }

  float acc[4] = {0.f,0.f,0.f,0.f};
  #pragma unroll
  for (int g=0;g<2;g++){
    #pragma unroll
    for (int h=0;h<2;h++){
      #pragma unroll
      for (int c=0;c<2;c++){
        float wr[16];
        #pragma unroll
        for (int q=0;q<16;q++) wr[q] = Wd[(size_t)(g*64+h*32+c*16+q)*64 + j];
        #pragma unroll
        for (int q=0;q<16;q++){
          int b = c*16+q;
          #pragma unroll
          for (int t=0;t<4;t++){
            uint32_t wv = h ? whi[g][t] : wlo[g][t];
            acc[t] = __fadd_rn(acc[t], bitmaskf(wv, b, wr[q]));
          }
        }
      }
    }
  }

  float v = 0.0f;
  double ysum = 0.0;
  #pragma unroll
  for (int t=0;t<4;t++){
    float a = __fadd_rn(acc[t], bdj);
    bool s = lif32(v, a);
    uint64_t bw = __ballot(s);
    if (j==0) sw[row] = bw;
    __syncthreads();
    uint64_t m = sw[0] & sw[1];
    __syncthreads();
    double term = ((m>>j)&1ull) ? wrecj : 0.0;
    #pragma unroll
    for (int off=1; off<64; off<<=1) term += shflxor_d(term, off);
    ysum += term;
  }
  if (tid==0) out[i] = (float)(1.0/(1.0 + exp(-0.25*ysum)));
}

// ---------------- Launcher ----------------
extern "C" void kernel_launch(void* const* d_in, const int* in_sizes, int n_in,
                              void* d_out, int out_size, void* d_ws, size_t ws_size,
                              hipStream_t stream) {
  const float* x    = (const float*)d_in[0];
  const float* W1   = (const float*)d_in[1];
  const float* W2   = (const float*)d_in[2];
  const float* Wd   = (const float*)d_in[3];
  const float* bd   = (const float*)d_in[4];
  const float* wrec = (const float*)d_in[5];
  const float* ew   = (const float*)d_in[6];
  const int* esrc   = (const int*)d_in[7];
  const int* edst   = (const int*)d_in[8];
  const int* ns     = (const int*)d_in[9];
  const int* nt     = (const int*)d_in[10];
  float* out = (float*)d_out;
  (void)in_sizes; (void)n_in; (void)out_size; (void)ws_size;

  // workspace layout (~41 MB)
  char* p = (char*)d_ws;
  uint64_t* inpb = (uint64_t*)p; p += (size_t)NN*16*8;
  uint64_t* hs0b = (uint64_t*)p; p += (size_t)NN*16*8;
  uint64_t* zs0b = (uint64_t*)p; p += (size_t)NN*16*8;
  uint64_t* hs1b = (uint64_t*)p; p += (size_t)NN*32*8;
  uint64_t* zs1b = (uint64_t*)p; p += (size_t)NN*8*8;
  int*   eidx = (int*)p;   p += (size_t)NE*4;
  int*   csrc = (int*)p;   p += (size_t)NE*4;
  float* cw   = (float*)p; p += (size_t)NE*4;
  int*   cnt  = (int*)p;   p += (size_t)(NN+2)*4;
  int*   rp   = (int*)p;   p += (size_t)(NN+2)*4;
  int*   cur  = (int*)p;   p += (size_t)(NN+2)*4;

  // host-side key chain: key=(0,42); kt=fold_in(key,t); k1,k2=split(kt)
  K8 K1, K2;
  for (int t=0;t<4;t++){
    uint32_t kt0,kt1;
    tf2x32(0u, 42u, 0u, (uint32_t)t, kt0, kt1);
#if JAX_PARTITIONABLE
    tf2x32(kt0, kt1, 0u, 0u, K1.a[t], K1.b[t]);
    tf2x32(kt0, kt1, 0u, 1u, K2.a[t], K2.b[t]);
#else
    uint32_t A0,B0,A1,B1;
    tf2x32(kt0, kt1, 0u, 2u, A0, B0);
    tf2x32(kt0, kt1, 1u, 3u, A1, B1);
    K1.a[t]=A0; K1.b[t]=A1; K2.a[t]=B0; K2.b[t]=B1;
#endif
  }

  // CSR build (deterministic via per-row sort by edge id)
  hipMemsetAsync(cnt, 0, (size_t)NN*4, stream);
  k_hist   <<<(NE+255)/256, 256, 0, stream>>>(edst, cnt);
  k_scan   <<<1, 1024, 0, stream>>>(cnt, rp, cur);
  k_scatter<<<(NE+255)/256, 256, 0, stream>>>(edst, cur, eidx);
  k_sortrow<<<(NN+255)/256, 256, 0, stream>>>(rp, eidx, esrc, ew, csrc, cw);

  // stage-major pipeline, all T=4 per kernel, LIF state in registers (fp32)
  k_pois_x<<<NN, 256, 0, stream>>>(x, inpb, K1);
  k_h0    <<<NN, 256, 0, stream>>>(rp, csrc, cw, inpb, hs0b, K2);
  k_z0    <<<NN/16, 256, 0, stream>>>(hs0b, W1, zs0b);
  k_h1    <<<NN, 512, 0, stream>>>(rp, csrc, cw, zs0b, hs0b, hs1b);
  k_z1    <<<NN/16, 256, 0, stream>>>(hs1b, W2, zs1b);
  k_dec_y <<<NL, 128, 0, stream>>>(ns, nt, zs1b, Wd, bd, wrec, out);
}

// Round 22
// 1568.646 us; speedup vs baseline: 1.1637x; 1.0172x over previous
//
#include <hip/hip_runtime.h>
#include <stdint.h>
#include <math.h>

// Problem constants
#define NN    50000       // N_NODES
#define NE    400000      // N_EDGES
#define NL    50000       // N_LINKS
#define TOT   12800000    // NN*256

#define JAX_PARTITIONABLE 1

struct K8 { uint32_t a[4]; uint32_t b[4]; };

// ---------------- Threefry-2x32 (20 rounds) ----------------
__host__ __device__ inline uint32_t rotl32(uint32_t x, int r){ return (x<<r)|(x>>(32-r)); }

__host__ __device__ inline void tf2x32(uint32_t k0, uint32_t k1, uint32_t x0, uint32_t x1,
                                       uint32_t &o0, uint32_t &o1) {
  uint32_t k2 = k0 ^ k1 ^ 0x1BD11BDAu;
  x0 += k0; x1 += k1;
#define TFR(r) { x0 += x1; x1 = rotl32(x1,(r)); x1 ^= x0; }
  TFR(13) TFR(15) TFR(26) TFR(6)
  x0 += k1; x1 += k2 + 1u;
  TFR(17) TFR(29) TFR(16) TFR(24)
  x0 += k2; x1 += k0 + 2u;
  TFR(13) TFR(15) TFR(26) TFR(6)
  x0 += k0; x1 += k1 + 3u;
  TFR(17) TFR(29) TFR(16) TFR(24)
  x0 += k1; x1 += k2 + 4u;
  TFR(13) TFR(15) TFR(26) TFR(6)
  x0 += k2; x1 += k0 + 5u;
#undef TFR
  o0 = x0; o1 = x1;
}

__device__ inline float u01(uint32_t b){
  return __uint_as_float((b>>9) | 0x3f800000u) - 1.0f;   // [1,2) - 1, exact
}

__device__ inline uint32_t jax_bits32(uint32_t ka, uint32_t kb, uint32_t i, uint32_t total){
#if JAX_PARTITIONABLE
  uint32_t o0,o1; tf2x32(ka,kb, 0u, i, o0,o1); return o0^o1;
#else
  uint32_t h = total>>1; uint32_t o0,o1;
  if (i < h){ tf2x32(ka,kb, i, i+h, o0,o1); return o0; }
  else      { tf2x32(ka,kb, i-h, i, o0,o1); return o1; }
#endif
}

__device__ inline double shflxor_d(double x, int m){
  union { double d; int i[2]; } u; u.d = x;
  u.i[0] = __shfl_xor(u.i[0], m, 64);
  u.i[1] = __shfl_xor(u.i[1], m, 64);
  return u.d;
}

// exact fp32 LIF step: v = fl(fl(v*0.5)+a); d = fl(v-0.2); s=(d>=0); v = s?d:v
__device__ inline bool lif32(float &v, float a){
  v = __fadd_rn(__fmul_rn(v, 0.5f), a);
  float d = __fsub_rn(v, 0.2f);
  bool s = (d >= 0.0f);
  v = s ? d : v;
  return s;
}

// force a value to live in a VGPR
#define FORCE_V(x) asm volatile("" : "+v"(x))

// wr if bit b of w set, else +0.0f — used in decoder (small)
__device__ inline float bitmaskf(uint32_t w, int b, float wr){
#if __has_builtin(__builtin_amdgcn_sbfe)
  int m = __builtin_amdgcn_sbfe((int)w, b, 1);
#else
  int m = ((int)(w << (31-b))) >> 31;
#endif
  return __int_as_float(__float_as_int(wr) & m);
}

// ---------------- CSR build (by dst), deterministic edge order ----------------
__global__ __launch_bounds__(256) void k_hist(const int* __restrict__ dst, int* __restrict__ cnt){
  int e = blockIdx.x*256 + threadIdx.x;
  if (e < NE) atomicAdd(&cnt[dst[e]], 1);
}

// wave-shuffle scan: 3 barriers per 1024-chunk (was ~20)
__global__ __launch_bounds__(1024) void k_scan(const int* __restrict__ cnt,
    int* __restrict__ rp, int* __restrict__ cur){
  __shared__ int ws[16];
  __shared__ int wp[17];
  int tid = threadIdx.x;
  int lane = tid & 63, wid = tid >> 6;
  int carry = 0;
  for (int base=0; base<NN; base+=1024){
    int v = (base+tid < NN) ? cnt[base+tid] : 0;
    int x = v;
    #pragma unroll
    for (int off=1; off<64; off<<=1){
      int u = __shfl_up(x, off, 64);
      if (lane >= off) x += u;
    }
    if (lane==63) ws[wid] = x;
    __syncthreads();
    if (wid==0){
      int s = (lane<16) ? ws[lane] : 0;
      #pragma unroll
      for (int off=1; off<16; off<<=1){
        int u = __shfl_up(s, off, 64);
        if (lane >= off) s += u;
      }
      if (lane<16) wp[lane+1] = s;
      if (lane==0) wp[0] = 0;
    }
    __syncthreads();
    int excl = x - v + wp[wid] + carry;
    if (base+tid < NN){ rp[base+tid] = excl; cur[base+tid] = excl; }
    carry += wp[16];
    __syncthreads();
  }
  if (tid==0) rp[NN] = NE;
}

__global__ __launch_bounds__(256) void k_scatter(const int* __restrict__ dst,
    int* __restrict__ cur, int* __restrict__ eidx){
  int e = blockIdx.x*256 + threadIdx.x;
  if (e < NE){ int p = atomicAdd(&cur[dst[e]], 1); eidx[p] = e; }
}

__global__ __launch_bounds__(256) void k_sortrow(const int* __restrict__ rp,
    int* __restrict__ eidx, const int* __restrict__ esrc, const float* __restrict__ ew,
    int* __restrict__ csrc, float* __restrict__ cw){
  int n = blockIdx.x*256 + threadIdx.x;
  if (n >= NN) return;
  int lo = rp[n], hi = rp[n+1];
  for (int a=lo+1; a<hi; a++){
    int k = eidx[a]; int b = a-1;
    while (b>=lo && eidx[b]>k){ eidx[b+1]=eidx[b]; b--; }
    eidx[b+1] = k;
  }
  for (int p=lo; p<hi; p++){ int e = eidx[p]; csrc[p] = esrc[e]; cw[p] = ew[e]; }
}

// Plane layouts (t innermost, 32B per (node,word)):
//   inpb/hs0b/zs0b : [node][w(4)][t(4)]   (NN*16 words)
//   hs1b           : [node][w(8)][t(4)]   (NN*32 words)
//   zs1b           : [node][w(2)][t(4)]   (NN*8  words)

// ---------------- Stage A: inp(t) = poisson(x, k1[t]) ----------------
__global__ __launch_bounds__(256) void k_pois_x(const float* __restrict__ x,
    uint64_t* __restrict__ bits, K8 K){
  int n = blockIdx.x, f = threadIdx.x;
  uint32_t i = (uint32_t)n*256u + (uint32_t)f;
  float xv = x[i];
  uint64_t pack[4];
  #pragma unroll
  for (int t=0;t<4;t++){
    bool b = (u01(jax_bits32(K.a[t],K.b[t], i, TOT)) <= xv);
    pack[t] = __ballot(b);
  }
  if ((f & 63)==0){
    uint64_t* dst = bits + ((size_t)n*4 + (f>>6))*4;
    #pragma unroll
    for (int t=0;t<4;t++) dst[t] = pack[t];
  }
}

// ---------------- Stage B: h0(t) fp32 gather (edge order) + poisson(h0,k2) ----------------
// 1-deep software pipeline: issue edge p+1's loads before accumulating edge p.
// fp32 add ORDER is unchanged (exactness vs reference preserved).
__global__ __launch_bounds__(256) void k_h0(const int* __restrict__ rp,
    const int* __restrict__ csrc, const float* __restrict__ cw,
    const uint64_t* __restrict__ inb, uint64_t* __restrict__ outb, K8 K){
  int n = blockIdx.x, f = threadIdx.x;
  int wi = f>>6, sh = f&63;
  int lo = rp[n], hi = rp[n+1];
  float a[4] = {0.f,0.f,0.f,0.f};
  if (lo < hi){
    int s = csrc[lo];
    float w = cw[lo];
    const uint64_t* bp = inb + ((size_t)s*4 + wi)*4;
    uint64_t b0=bp[0], b1=bp[1], b2=bp[2], b3=bp[3];
    for (int p=lo+1; p<hi; p++){
      int s2 = csrc[p];
      float w2 = cw[p];
      const uint64_t* bp2 = inb + ((size_t)s2*4 + wi)*4;
      uint64_t n0=bp2[0], n1=bp2[1], n2=bp2[2], n3=bp2[3];
      a[0] = __fadd_rn(a[0], ((b0>>sh)&1ull) ? w : 0.0f);
      a[1] = __fadd_rn(a[1], ((b1>>sh)&1ull) ? w : 0.0f);
      a[2] = __fadd_rn(a[2], ((b2>>sh)&1ull) ? w : 0.0f);
      a[3] = __fadd_rn(a[3], ((b3>>sh)&1ull) ? w : 0.0f);
      b0=n0; b1=n1; b2=n2; b3=n3; w=w2;
    }
    a[0] = __fadd_rn(a[0], ((b0>>sh)&1ull) ? w : 0.0f);
    a[1] = __fadd_rn(a[1], ((b1>>sh)&1ull) ? w : 0.0f);
    a[2] = __fadd_rn(a[2], ((b2>>sh)&1ull) ? w : 0.0f);
    a[3] = __fadd_rn(a[3], ((b3>>sh)&1ull) ? w : 0.0f);
  }
  uint32_t i = (uint32_t)n*256u + (uint32_t)f;
  uint64_t pack[4];
  #pragma unroll
  for (int t=0;t<4;t++){
    bool b = (u01(jax_bits32(K.a[t],K.b[t], i, TOT)) <= a[t]);
    pack[t] = __ballot(b);
  }
  if (sh==0){
    uint64_t* dst = outb + ((size_t)n*4 + wi)*4;
    #pragma unroll
    for (int t=0;t<4;t++) dst[t] = pack[t];
  }
}

// ---------------- Stage C: z0 = LIF_t(hs0 @ W1)  (K=256, M=256) ----------------
// 16 nodes/block (4 waves x 4-node group), 4 cols/thread (col = lane+64cc).
// Per q: 4 coalesced wr loads + 4 broadcast ds_read_b128 + 64 v_fma; unroll 8
// (mirrors the k_z1 v5 win: deeper load batching at preserved occupancy).
__global__ __launch_bounds__(256, 2) void k_z0(const uint64_t* __restrict__ inb,
    const float* __restrict__ W, uint64_t* __restrict__ outb){
  __shared__ __align__(16) float sp[16*64*4];    // [i(16)][k(64)][t(4)] 16KB
  int tid = threadIdx.x;
  int g = tid>>6, lane = tid&63;                 // wave = node group
  int n0 = blockIdx.x*16;
  float acc[4][4][4];                            // [t][i][cc]
  #pragma unroll
  for (int t=0;t<4;t++)
    #pragma unroll
    for (int i=0;i<4;i++)
      #pragma unroll
      for (int c=0;c<4;c++) acc[t][i][c]=0.0f;

  for (int kt=0; kt<4; kt++){
    #pragma unroll
    for (int rep=0; rep<4; rep++){
      int idx = rep*256 + tid;
      int i = idx>>6, k = idx&63;
      const uint64_t* bp = inb + (((size_t)(n0+i))*4 + kt)*4;
      uint64_t w0=bp[0], w1=bp[1], w2=bp[2], w3=bp[3];
      float4 f;
      f.x = ((w0>>k)&1ull) ? 1.0f : 0.0f;
      f.y = ((w1>>k)&1ull) ? 1.0f : 0.0f;
      f.z = ((w2>>k)&1ull) ? 1.0f : 0.0f;
      f.w = ((w3>>k)&1ull) ? 1.0f : 0.0f;
      *(float4*)&sp[(i*64+k)*4] = f;
    }
    __syncthreads();
    const float* Wrow = W + (size_t)(kt*64)*256 + lane;
    #pragma unroll 8
    for (int q=0;q<64;q++){
      const float* wb = Wrow + (size_t)q*256;
      float wr0 = wb[0], wr1 = wb[64], wr2 = wb[128], wr3 = wb[192];
      float4 s0 = *(const float4*)&sp[((g*4+0)*64+q)*4];
      float4 s1 = *(const float4*)&sp[((g*4+1)*64+q)*4];
      float4 s2 = *(const float4*)&sp[((g*4+2)*64+q)*4];
      float4 s3 = *(const float4*)&sp[((g*4+3)*64+q)*4];
      #define FMA4(ti, sv) \
        acc[ti][0][0]=__fmaf_rn(s0.sv,wr0,acc[ti][0][0]); acc[ti][0][1]=__fmaf_rn(s0.sv,wr1,acc[ti][0][1]); \
        acc[ti][0][2]=__fmaf_rn(s0.sv,wr2,acc[ti][0][2]); acc[ti][0][3]=__fmaf_rn(s0.sv,wr3,acc[ti][0][3]); \
        acc[ti][1][0]=__fmaf_rn(s1.sv,wr0,acc[ti][1][0]); acc[ti][1][1]=__fmaf_rn(s1.sv,wr1,acc[ti][1][1]); \
        acc[ti][1][2]=__fmaf_rn(s1.sv,wr2,acc[ti][1][2]); acc[ti][1][3]=__fmaf_rn(s1.sv,wr3,acc[ti][1][3]); \
        acc[ti][2][0]=__fmaf_rn(s2.sv,wr0,acc[ti][2][0]); acc[ti][2][1]=__fmaf_rn(s2.sv,wr1,acc[ti][2][1]); \
        acc[ti][2][2]=__fmaf_rn(s2.sv,wr2,acc[ti][2][2]); acc[ti][2][3]=__fmaf_rn(s2.sv,wr3,acc[ti][2][3]); \
        acc[ti][3][0]=__fmaf_rn(s3.sv,wr0,acc[ti][3][0]); acc[ti][3][1]=__fmaf_rn(s3.sv,wr1,acc[ti][3][1]); \
        acc[ti][3][2]=__fmaf_rn(s3.sv,wr2,acc[ti][3][2]); acc[ti][3][3]=__fmaf_rn(s3.sv,wr3,acc[ti][3][3]);
      FMA4(0, x) FMA4(1, y) FMA4(2, z) FMA4(3, w)
      #undef FMA4
    }
    __syncthreads();
  }

  #pragma unroll
  for (int i=0;i<4;i++){
    int node = n0 + g*4 + i;
    float v[4] = {0.f,0.f,0.f,0.f};
    #pragma unroll
    for (int t=0;t<4;t++){
      uint64_t b[4];
      #pragma unroll
      for (int c=0;c<4;c++){
        bool s = lif32(v[c], acc[t][i][c]);
        b[c] = __ballot(s);
      }
      if (lane==0){
        #pragma unroll
        for (int c=0;c<4;c++) outb[((size_t)node*4 + c)*4 + t] = b[c];
      }
    }
  }
}

// ---------------- Stage D: h1(t) gather over concat(zs0,hs0), LIF -> hs1 ----------------
// Same 1-deep software pipeline as k_h0; add order unchanged.
__global__ __launch_bounds__(512) void k_h1(const int* __restrict__ rp,
    const int* __restrict__ csrc, const float* __restrict__ cw,
    const uint64_t* __restrict__ zs0b, const uint64_t* __restrict__ hs0b,
    uint64_t* __restrict__ hs1b){
  int n = blockIdx.x, f = threadIdx.x;           // f in [0,512)
  int wi = f>>6, sh = f&63;
  const uint64_t* plane = (wi<4) ? zs0b : hs0b;
  int wo = wi & 3;
  int lo = rp[n], hi = rp[n+1];
  float a[4] = {0.f,0.f,0.f,0.f};
  if (lo < hi){
    int s = csrc[lo];
    float w = cw[lo];
    const uint64_t* bp = plane + ((size_t)s*4 + wo)*4;
    uint64_t b0=bp[0], b1=bp[1], b2=bp[2], b3=bp[3];
    for (int p=lo+1; p<hi; p++){
      int s2 = csrc[p];
      float w2 = cw[p];
      const uint64_t* bp2 = plane + ((size_t)s2*4 + wo)*4;
      uint64_t n0=bp2[0], n1=bp2[1], n2=bp2[2], n3=bp2[3];
      a[0] = __fadd_rn(a[0], ((b0>>sh)&1ull) ? w : 0.0f);
      a[1] = __fadd_rn(a[1], ((b1>>sh)&1ull) ? w : 0.0f);
      a[2] = __fadd_rn(a[2], ((b2>>sh)&1ull) ? w : 0.0f);
      a[3] = __fadd_rn(a[3], ((b3>>sh)&1ull) ? w : 0.0f);
      b0=n0; b1=n1; b2=n2; b3=n3; w=w2;
    }
    a[0] = __fadd_rn(a[0], ((b0>>sh)&1ull) ? w : 0.0f);
    a[1] = __fadd_rn(a[1], ((b1>>sh)&1ull) ? w : 0.0f);
    a[2] = __fadd_rn(a[2], ((b2>>sh)&1ull) ? w : 0.0f);
    a[3] = __fadd_rn(a[3], ((b3>>sh)&1ull) ? w : 0.0f);
  }
  float v = 0.0f;
  uint64_t pack[4];
  #pragma unroll
  for (int t=0;t<4;t++){
    bool s = lif32(v, a[t]);
    pack[t] = __ballot(s);
  }
  if (sh==0){
    uint64_t* dst = hs1b + ((size_t)n*8 + wi)*4;
    #pragma unroll
    for (int t=0;t<4;t++) dst[t] = pack[t];
  }
}

// ---------------- Stage E: z1 = LIF_t(hs1 @ W2)  (K=512, M=128) ----------------
// v5 = v2 (measured 385us, occ 38.7%) with deeper load batching: unroll 8.
// Measured r21: 374.8us, VALU 70.1%, occ 38.2%, VGPR 60. KEPT.
__global__ __launch_bounds__(256, 2) void k_z1(const uint64_t* __restrict__ inb,
    const float* __restrict__ W, uint64_t* __restrict__ outb){
  __shared__ __align__(16) float sp[16*64*4];    // [i(16)][k(64)][t(4)] 16KB
  int tid = threadIdx.x;
  int g = tid>>6, lane = tid&63;                 // wave = node group
  int n0 = blockIdx.x*16;
  float acc[4][4][2];                            // [t][i][c]
  #pragma unroll
  for (int t=0;t<4;t++)
    #pragma unroll
    for (int i=0;i<4;i++){ acc[t][i][0]=0.0f; acc[t][i][1]=0.0f; }

  for (int kt=0; kt<8; kt++){
    #pragma unroll
    for (int rep=0; rep<4; rep++){
      int idx = rep*256 + tid;
      int i = idx>>6, k = idx&63;
      const uint64_t* bp = inb + (((size_t)(n0+i))*8 + kt)*4;
      uint64_t w0=bp[0], w1=bp[1], w2=bp[2], w3=bp[3];
      float4 f;
      f.x = ((w0>>k)&1ull) ? 1.0f : 0.0f;
      f.y = ((w1>>k)&1ull) ? 1.0f : 0.0f;
      f.z = ((w2>>k)&1ull) ? 1.0f : 0.0f;
      f.w = ((w3>>k)&1ull) ? 1.0f : 0.0f;
      *(float4*)&sp[(i*64+k)*4] = f;
    }
    __syncthreads();
    const float* Wrow = W + (size_t)(kt*64)*128 + lane;
    #pragma unroll 8
    for (int q=0;q<64;q++){
      const float* wb = Wrow + (size_t)q*128;
      float wr0 = wb[0], wr1 = wb[64];
      float4 s0 = *(const float4*)&sp[((g*4+0)*64+q)*4];
      float4 s1 = *(const float4*)&sp[((g*4+1)*64+q)*4];
      float4 s2 = *(const float4*)&sp[((g*4+2)*64+q)*4];
      float4 s3 = *(const float4*)&sp[((g*4+3)*64+q)*4];
      #define FMA2(ti, sv) \
        acc[ti][0][0]=__fmaf_rn(s0.sv,wr0,acc[ti][0][0]); acc[ti][0][1]=__fmaf_rn(s0.sv,wr1,acc[ti][0][1]); \
        acc[ti][1][0]=__fmaf_rn(s1.sv,wr0,acc[ti][1][0]); acc[ti][1][1]=__fmaf_rn(s1.sv,wr1,acc[ti][1][1]); \
        acc[ti][2][0]=__fmaf_rn(s2.sv,wr0,acc[ti][2][0]); acc[ti][2][1]=__fmaf_rn(s2.sv,wr1,acc[ti][2][1]); \
        acc[ti][3][0]=__fmaf_rn(s3.sv,wr0,acc[ti][3][0]); acc[ti][3][1]=__fmaf_rn(s3.sv,wr1,acc[ti][3][1]);
      FMA2(0, x) FMA2(1, y) FMA2(2, z) FMA2(3, w)
      #undef FMA2
    }
    __syncthreads();
  }

  #pragma unroll
  for (int i=0;i<4;i++){
    int node = n0 + g*4 + i;
    float v0 = 0.0f, v1 = 0.0f;
    #pragma unroll
    for (int t=0;t<4;t++){
      uint64_t b0, b1;
      { bool s = lif32(v0, acc[t][i][0]); b0 = __ballot(s); }   // cols 0..63
      { bool s = lif32(v1, acc[t][i][1]); b1 = __ballot(s); }   // cols 64..127
      if (lane==0){
        outb[((size_t)node*2 + 0)*4 + t] = b0;
        outb[((size_t)node*2 + 1)*4 + t] = b1;
      }
    }
  }
}

// ---------------- Stage F: decoder + y + sigmoid ----------------
__global__ __launch_bounds__(128) void k_dec_y(const int* __restrict__ ns,
    const int* __restrict__ nt, const uint64_t* __restrict__ zs1b,
    const float* __restrict__ Wd, const float* __restrict__ bd,
    const float* __restrict__ wrec, float* __restrict__ out){
  int i = blockIdx.x;
  int tid = threadIdx.x;
  int row = tid>>6, j = tid&63;
  int node = row ? nt[i] : ns[i];
  float bdj = bd[j];
  double wrecj = (double)wrec[j];
  __shared__ uint64_t sw[2];

  uint32_t wlo[2][4], whi[2][4];
  const uint64_t* bp = zs1b + (size_t)node*8;
  #pragma unroll
  for (int g=0;g<2;g++)
    #pragma unroll
    for (int t=0;t<4;t++){
      uint64_t w8 = bp[g*4+t];
      wlo[g][t] = (uint32_t)w8;
      whi[g][t] = (uint32_t)(w8>>32);
      FORCE_V(wlo[g][t]); FORCE_V(whi[g][t]);
    }

  float acc[4] = {0.f,0.f,0.f,0.f};
  #pragma unroll
  for (int g=0;g<2;g++){
    #pragma unroll
    for (int h=0;h<2;h++){
      #pragma unroll
      for (int c=0;c<2;c++){
        float wr[16];
        #pragma unroll
        for (int q=0;q<16;q++) wr[q] = Wd[(size_t)(g*64+h*32+c*16+q)*64 + j];
        #pragma unroll
        for (int q=0;q<16;q++){
          int b = c*16+q;
          #pragma unroll
          for (int t=0;t<4;t++){
            uint32_t wv = h ? whi[g][t] : wlo[g][t];
            acc[t] = __fadd_rn(acc[t], bitmaskf(wv, b, wr[q]));
          }
        }
      }
    }
  }

  float v = 0.0f;
  double ysum = 0.0;
  #pragma unroll
  for (int t=0;t<4;t++){
    float a = __fadd_rn(acc[t], bdj);
    bool s = lif32(v, a);
    uint64_t bw = __ballot(s);
    if (j==0) sw[row] = bw;
    __syncthreads();
    uint64_t m = sw[0] & sw[1];
    __syncthreads();
    double term = ((m>>j)&1ull) ? wrecj : 0.0;
    #pragma unroll
    for (int off=1; off<64; off<<=1) term += shflxor_d(term, off);
    ysum += term;
  }
  if (tid==0) out[i] = (float)(1.0/(1.0 + exp(-0.25*ysum)));
}

// ---------------- Launcher ----------------
extern "C" void kernel_launch(void* const* d_in, const int* in_sizes, int n_in,
                              void* d_out, int out_size, void* d_ws, size_t ws_size,
                              hipStream_t stream) {
  const float* x    = (const float*)d_in[0];
  const float* W1   = (const float*)d_in[1];
  const float* W2   = (const float*)d_in[2];
  const float* Wd   = (const float*)d_in[3];
  const float* bd   = (const float*)d_in[4];
  const float* wrec = (const float*)d_in[5];
  const float* ew   = (const float*)d_in[6];
  const int* esrc   = (const int*)d_in[7];
  const int* edst   = (const int*)d_in[8];
  const int* ns     = (const int*)d_in[9];
  const int* nt     = (const int*)d_in[10];
  float* out = (float*)d_out;
  (void)in_sizes; (void)n_in; (void)out_size; (void)ws_size;

  // workspace layout (~41 MB)
  char* p = (char*)d_ws;
  uint64_t* inpb = (uint64_t*)p; p += (size_t)NN*16*8;
  uint64_t* hs0b = (uint64_t*)p; p += (size_t)NN*16*8;
  uint64_t* zs0b = (uint64_t*)p; p += (size_t)NN*16*8;
  uint64_t* hs1b = (uint64_t*)p; p += (size_t)NN*32*8;
  uint64_t* zs1b = (uint64_t*)p; p += (size_t)NN*8*8;
  int*   eidx = (int*)p;   p += (size_t)NE*4;
  int*   csrc = (int*)p;   p += (size_t)NE*4;
  float* cw   = (float*)p; p += (size_t)NE*4;
  int*   cnt  = (int*)p;   p += (size_t)(NN+2)*4;
  int*   rp   = (int*)p;   p += (size_t)(NN+2)*4;
  int*   cur  = (int*)p;   p += (size_t)(NN+2)*4;

  // host-side key chain: key=(0,42); kt=fold_in(key,t); k1,k2=split(kt)
  K8 K1, K2;
  for (int t=0;t<4;t++){
    uint32_t kt0,kt1;
    tf2x32(0u, 42u, 0u, (uint32_t)t, kt0, kt1);
#if JAX_PARTITIONABLE
    tf2x32(kt0, kt1, 0u, 0u, K1.a[t], K1.b[t]);
    tf2x32(kt0, kt1, 0u, 1u, K2.a[t], K2.b[t]);
#else
    uint32_t A0,B0,A1,B1;
    tf2x32(kt0, kt1, 0u, 2u, A0, B0);
    tf2x32(kt0, kt1, 1u, 3u, A1, B1);
    K1.a[t]=A0; K1.b[t]=A1; K2.a[t]=B0; K2.b[t]=B1;
#endif
  }

  // CSR build (deterministic via per-row sort by edge id)
  hipMemsetAsync(cnt, 0, (size_t)NN*4, stream);
  k_hist   <<<(NE+255)/256, 256, 0, stream>>>(edst, cnt);
  k_scan   <<<1, 1024, 0, stream>>>(cnt, rp, cur);
  k_scatter<<<(NE+255)/256, 256, 0, stream>>>(edst, cur, eidx);
  k_sortrow<<<(NN+255)/256, 256, 0, stream>>>(rp, eidx, esrc, ew, csrc, cw);

  // stage-major pipeline, all T=4 per kernel, LIF state in registers (fp32)
  k_pois_x<<<NN, 256, 0, stream>>>(x, inpb, K1);
  k_h0    <<<NN, 256, 0, stream>>>(rp, csrc, cw, inpb, hs0b, K2);
  k_z0    <<<NN/16, 256, 0, stream>>>(hs0b, W1, zs0b);
  k_h1    <<<NN, 512, 0, stream>>>(rp, csrc, cw, zs0b, hs0b, hs1b);
  k_z1    <<<NN/16, 256, 0, stream>>>(hs1b, W2, zs1b);
  k_dec_y <<<NL, 128, 0, stream>>>(ns, nt, zs1b, Wd, bd, wrec, out);
}